// Round 1
// baseline (3770.411 us; speedup 1.0000x reference)
//
#include <hip/hip_runtime.h>
#include <math.h>

// DASCO forward: MHA->adjacency, 2 gated dual-GCN layers, projection,
// symmetric contrastive scope loss -> scalar.
// B=32, S=512, D=768, M=384, heads=8, dk=96. All fp32 (no fp32 MFMA on CDNA4;
// exp(x/0.07) amplifies error x14, so keep full precision in round 1).
//
// Workspace layout (phase-disjoint reuse), requires ws_size >= ~227 MB:
//   [0,48)MB    q            -> AH_sem(l0/l1)      -> h1[0,24) h2[24,48)
//   [48,96)MB   k            -> AH_dep(l0/l1)      -> G11[48,80)
//   [80,112)MB                                        G12
//   [96,128)MB  adj_ag (dead before G12/G21 written)
//   [112,144)MB                                       G21
//   [128,160)MB score chunk (attention phase only)
//   [128,152)MB I_sem (layers+proj phase)
//   [144,176)MB                                       G22
//   [152,176)MB I_dep / I_com
//   [176,200)MB H
//   [200,224)MB Hout
//   [224,226)MB t1 (elu intermediate, B*S*32)
//   [226,..)    loss[B*S]

#define TM 64
#define TN 64
#define TK 16

// ---------------- generic tiled GEMM ----------------
// C[z][m,n] = sum_k A[z][m,k] * (transB ? B[z][n,k] : B[z][k,n]) + bias[n]
// batch offset: aOff = (z/zInner)*sAo + (z%zInner)*sAi  (same for B), cOff = z*sC
// act: 0 none, 1 relu, 2 elu
__global__ __launch_bounds__(256) void gemm_kernel(
    const float* __restrict__ A, const float* __restrict__ B,
    const float* __restrict__ bias, float* __restrict__ C,
    int M, int N, int K, int lda, int ldb, int ldc,
    long sAo, long sAi, long sBo, long sBi, int zInner, long sC,
    int transB, int act)
{
    __shared__ float As[TK][TM + 1];
    __shared__ float Bs[TK][TN + 1];
    int z = blockIdx.z;
    long aBase = (long)(z / zInner) * sAo + (long)(z % zInner) * sAi;
    long bBase = (long)(z / zInner) * sBo + (long)(z % zInner) * sBi;
    long cBase = (long)z * sC;
    int m0 = blockIdx.y * TM, n0 = blockIdx.x * TN;
    int tid = threadIdx.x;
    int tm = tid >> 4, tn = tid & 15;

    float acc[4][4];
#pragma unroll
    for (int i = 0; i < 4; i++)
#pragma unroll
        for (int j = 0; j < 4; j++) acc[i][j] = 0.f;

    int ar = tid >> 2, ac = (tid & 3) * 4;       // A loader: 64 rows x 16 k
    int bkr = tid >> 4, bnc = (tid & 15) * 4;    // B NN loader: 16 k x 64 n
    int bnr = tid >> 2, bkc = (tid & 3) * 4;     // B NT loader: 64 n x 16 k

    for (int k0 = 0; k0 < K; k0 += TK) {
        float4 av = *(const float4*)(A + aBase + (long)(m0 + ar) * lda + (k0 + ac));
        As[ac + 0][ar] = av.x; As[ac + 1][ar] = av.y;
        As[ac + 2][ar] = av.z; As[ac + 3][ar] = av.w;
        if (!transB) {
            int n = n0 + bnc;
            float4 bv = make_float4(0.f, 0.f, 0.f, 0.f);
            if (n < N) bv = *(const float4*)(B + bBase + (long)(k0 + bkr) * ldb + n);
            Bs[bkr][bnc + 0] = bv.x; Bs[bkr][bnc + 1] = bv.y;
            Bs[bkr][bnc + 2] = bv.z; Bs[bkr][bnc + 3] = bv.w;
        } else {
            int n = n0 + bnr;
            float4 bv = make_float4(0.f, 0.f, 0.f, 0.f);
            if (n < N) bv = *(const float4*)(B + bBase + (long)n * ldb + (k0 + bkc));
            Bs[bkc + 0][bnr] = bv.x; Bs[bkc + 1][bnr] = bv.y;
            Bs[bkc + 2][bnr] = bv.z; Bs[bkc + 3][bnr] = bv.w;
        }
        __syncthreads();
#pragma unroll
        for (int kk = 0; kk < TK; ++kk) {
            float a0 = As[kk][tm * 4 + 0], a1 = As[kk][tm * 4 + 1];
            float a2 = As[kk][tm * 4 + 2], a3 = As[kk][tm * 4 + 3];
            float b0 = Bs[kk][tn * 4 + 0], b1 = Bs[kk][tn * 4 + 1];
            float b2 = Bs[kk][tn * 4 + 2], b3 = Bs[kk][tn * 4 + 3];
            acc[0][0] += a0 * b0; acc[0][1] += a0 * b1; acc[0][2] += a0 * b2; acc[0][3] += a0 * b3;
            acc[1][0] += a1 * b0; acc[1][1] += a1 * b1; acc[1][2] += a1 * b2; acc[1][3] += a1 * b3;
            acc[2][0] += a2 * b0; acc[2][1] += a2 * b1; acc[2][2] += a2 * b2; acc[2][3] += a2 * b3;
            acc[3][0] += a3 * b0; acc[3][1] += a3 * b1; acc[3][2] += a3 * b2; acc[3][3] += a3 * b3;
        }
        __syncthreads();
    }
#pragma unroll
    for (int i = 0; i < 4; i++) {
        int m = m0 + tm * 4 + i;
#pragma unroll
        for (int j = 0; j < 4; j++) {
            int n = n0 + tn * 4 + j;
            if (n < N) {
                float v = acc[i][j] + (bias ? bias[n] : 0.f);
                if (act == 1) v = fmaxf(v, 0.f);
                else if (act == 2) v = (v > 0.f) ? v : expm1f(v);
                C[cBase + (long)m * ldc + n] = v;
            }
        }
    }
}

// ---------------- attention softmax + head-mean + diag/mask -> adj_ag ----------------
// scores: [nb*8][S][S] raw q.k (unscaled). adj_ag[b,s,t] =
//   rowmask[s] * (t==s ? 1 : colmask[t] * mean_h softmax_t(scores*scale))
__global__ __launch_bounds__(256) void softmax_combine(
    const float* __restrict__ scores, const int* __restrict__ attn_mask,
    float* __restrict__ adj_ag, int b0)
{
    const int S = 512;
    int s = blockIdx.x, bl = blockIdx.y, b = b0 + bl;
    int tid = threadIdx.x;
    const float scale = 0.1020620726159658f;  // 1/sqrt(96)
    int t0 = tid, t1 = tid + 256;
    int cm0 = attn_mask[b * S + t0], cm1 = attn_mask[b * S + t1];
    float vals[8][2], part[8];
#pragma unroll
    for (int h = 0; h < 8; ++h) {
        long rb = ((long)(bl * 8 + h) * S + s) * S;
        float r0 = scores[rb + t0], r1 = scores[rb + t1];
        vals[h][0] = cm0 ? expf(r0 * scale) : 0.f;
        vals[h][1] = cm1 ? expf(r1 * scale) : 0.f;
        part[h] = vals[h][0] + vals[h][1];
    }
    __shared__ float red[4][8];
    __shared__ float linv[8];
    int lane = tid & 63, w = tid >> 6;
#pragma unroll
    for (int h = 0; h < 8; ++h) {
        float v = part[h];
        for (int o = 32; o > 0; o >>= 1) v += __shfl_down(v, o);
        if (lane == 0) red[w][h] = v;
    }
    __syncthreads();
    if (tid < 8) {
        float l = red[0][tid] + red[1][tid] + red[2][tid] + red[3][tid];
        linv[tid] = 1.f / fmaxf(l, 1e-30f);
    }
    __syncthreads();
    float rowmask = attn_mask[b * S + s] ? 1.f : 0.f;
    float a0 = 0.f, a1 = 0.f;
#pragma unroll
    for (int h = 0; h < 8; ++h) { a0 += vals[h][0] * linv[h]; a1 += vals[h][1] * linv[h]; }
    a0 *= 0.125f; a1 *= 0.125f;
    if (t0 == s) a0 = 1.f;
    if (t1 == s) a1 = 1.f;
    long ob = ((long)b * S + s) * S;
    adj_ag[ob + t0] = rowmask * a0;
    adj_ag[ob + t1] = rowmask * a1;
}

// ---------------- elementwise ----------------
// I_com = (1 - 0.6*sig(I_dep))*I_sem + 0.6*sig(I_dep)*I_dep   (written into Idep)
__global__ void gcn_combine(const float* __restrict__ Isem, float* __restrict__ Idep, long n)
{
    long i = (long)blockIdx.x * blockDim.x + threadIdx.x;
    if (i < n) {
        float d = Idep[i], s = Isem[i];
        float g = 0.6f / (1.f + expf(-d));
        Idep[i] = (1.f - g) * s + g * d;
    }
}

// H = sig(H)*Hout + (1-sig(H))*H   (in place)
__global__ void gate_combine(float* __restrict__ H, const float* __restrict__ Hout, long n)
{
    long i = (long)blockIdx.x * blockDim.x + threadIdx.x;
    if (i < n) {
        float h = H[i];
        float g = 1.f / (1.f + expf(-h));
        H[i] = g * Hout[i] + (1.f - g) * h;
    }
}

// row L2-normalize, in place (z / max(||z||, 1e-12))
__global__ __launch_bounds__(128) void rownorm(float* __restrict__ h1, float* __restrict__ h2, int Dm)
{
    float* p = (blockIdx.y ? h2 : h1) + (long)blockIdx.x * Dm;
    int tid = threadIdx.x;
    float ss = 0.f;
    for (int i = tid; i < Dm; i += 128) { float v = p[i]; ss += v * v; }
    for (int o = 32; o > 0; o >>= 1) ss += __shfl_down(ss, o);
    __shared__ float sb[2];
    __shared__ float scale;
    if ((tid & 63) == 0) sb[tid >> 6] = ss;
    __syncthreads();
    if (tid == 0) scale = 1.f / fmaxf(sqrtf(sb[0] + sb[1]), 1e-12f);
    __syncthreads();
    for (int i = tid; i < Dm; i += 128) p[i] *= scale;
}

// ---------------- fused symmetric scope loss per (b,s) row ----------------
__global__ __launch_bounds__(256) void loss_kernel(
    const float* __restrict__ G11, const float* __restrict__ G12,
    const float* __restrict__ G21, const float* __restrict__ G22,
    const int* __restrict__ s_mask, const int* __restrict__ a_mask,
    float* __restrict__ lossb)
{
    const int S = 512;
    int s = blockIdx.x, b = blockIdx.y;
    long base = ((long)b * S + s) * S;
    int tid = threadIdx.x;
    const float it = 1.f / 0.07f;
    float A = a_mask[b * S + s] ? 1.f : 0.f;
    float sms = s_mask[b * S + s] ? 1.f : 0.f;
    float d12 = G12[base + s], d21 = G21[base + s];
    float w1 = A * sms * d12, w2 = A * sms * d21;  // diag(w) for each direction
    float p[8];
#pragma unroll
    for (int h = 0; h < 8; h++) p[h] = 0.f;
#pragma unroll
    for (int j = 0; j < 2; j++) {
        int t = tid + j * 256;
        float smt = s_mask[b * S + t] ? 1.f : 0.f;
        float g11 = G11[base + t], g12 = G12[base + t];
        float g21 = G21[base + t], g22 = G22[base + t];
        if (t != s) {
            p[0] += expf(A * smt * g11 * it);        // as_refl off-diag (dir1)
            p[1] += expf(A * smt * g12 * w1 * it);   // weighted off-diag (dir1)
            p[4] += expf(A * smt * g22 * it);        // dir2
            p[5] += expf(A * smt * g21 * w2 * it);
        }
        p[2] += expf(A * g11 * it);                  // m_refl total (dir1)
        p[3] += expf(A * g12 * it);                  // m_between total (dir1)
        p[6] += expf(A * g22 * it);
        p[7] += expf(A * g21 * it);
    }
    __shared__ float red[4][8];
    int lane = tid & 63, w = tid >> 6;
#pragma unroll
    for (int h = 0; h < 8; h++) {
        float v = p[h];
        for (int o = 32; o > 0; o >>= 1) v += __shfl_down(v, o);
        if (lane == 0) red[w][h] = v;
    }
    __syncthreads();
    if (tid == 0) {
        float r[8];
#pragma unroll
        for (int h = 0; h < 8; h++) r[h] = red[0][h] + red[1][h] + red[2][h] + red[3][h];
        float g11ss = G11[base + s], g22ss = G22[base + s];
        float pos1 = expf(w1 * it) + r[0] + r[1];
        float alle1 = r[2] - expf(A * g11ss * it) + r[3];
        float pos2 = expf(w2 * it) + r[4] + r[5];
        float alle2 = r[6] - expf(A * g22ss * it) + r[7];
        float l1 = -logf(pos1 / alle1);
        float l2 = -logf(pos2 / alle2);
        lossb[b * S + s] = 0.5f * (l1 + l2);
    }
}

__global__ __launch_bounds__(256) void final_reduce(
    const float* __restrict__ lossb, float* __restrict__ out, int n)
{
    int tid = threadIdx.x;
    float s = 0.f;
    for (int i = tid; i < n; i += 256) s += lossb[i];
    for (int o = 32; o > 0; o >>= 1) s += __shfl_down(s, o);
    __shared__ float sb[4];
    if ((tid & 63) == 0) sb[tid >> 6] = s;
    __syncthreads();
    if (tid == 0) out[0] = (sb[0] + sb[1] + sb[2] + sb[3]) / (float)n;
}

// ---------------- host ----------------
static inline void gemm(hipStream_t st, const float* A, const float* B, const float* bias, float* C,
                        int M, int N, int K, int lda, int ldb, int ldc,
                        long sAo, long sAi, long sBo, long sBi, int zInner, long sC, int nz,
                        int transB, int act)
{
    dim3 g((N + TN - 1) / TN, (M + TM - 1) / TM, nz);
    gemm_kernel<<<g, 256, 0, st>>>(A, B, bias, C, M, N, K, lda, ldb, ldc,
                                   sAo, sAi, sBo, sBi, zInner, sC, transB, act);
}

extern "C" void kernel_launch(void* const* d_in, const int* in_sizes, int n_in,
                              void* d_out, int out_size, void* d_ws, size_t ws_size,
                              hipStream_t stream)
{
    const int B = 32, S = 512, D = 768, Mm = 384;
    const int MT = B * S;  // 16384
    const float* X    = (const float*)d_in[0];
    const float* adjm = (const float*)d_in[1];
    const int* attn_mask = (const int*)d_in[2];
    const int* s_mask    = (const int*)d_in[3];
    const int* a_mask    = (const int*)d_in[4];
    const float* Wq = (const float*)d_in[5],  *bq = (const float*)d_in[6];
    const float* Wk = (const float*)d_in[7],  *bk = (const float*)d_in[8];
    const float* semW0 = (const float*)d_in[9],  *semb0 = (const float*)d_in[10];
    const float* semW1 = (const float*)d_in[11], *semb1 = (const float*)d_in[12];
    const float* depW0 = (const float*)d_in[13], *depb0 = (const float*)d_in[14];
    const float* depW1 = (const float*)d_in[15], *depb1 = (const float*)d_in[16];
    const float* fc1W = (const float*)d_in[17], *fc1b = (const float*)d_in[18];
    const float* fc2W = (const float*)d_in[19], *fc2b = (const float*)d_in[20];
    const float* fc3W = (const float*)d_in[21], *fc3b = (const float*)d_in[22];
    const float* fc4W = (const float*)d_in[23], *fc4b = (const float*)d_in[24];

    char* ws = (char*)d_ws;
    const size_t MB = 1u << 20;
    float* q      = (float*)(ws + 0 * MB);     // 48MB
    float* kbuf   = (float*)(ws + 48 * MB);    // 48MB
    float* adj_ag = (float*)(ws + 96 * MB);    // 32MB
    float* scoreC = (float*)(ws + 128 * MB);   // 32MB (attention phase)
    float* Isem   = (float*)(ws + 128 * MB);   // 24MB (layer phase)
    float* Idep   = (float*)(ws + 152 * MB);   // 24MB
    float* H      = (float*)(ws + 176 * MB);   // 24MB
    float* Hout   = (float*)(ws + 200 * MB);   // 24MB
    float* t1     = (float*)(ws + 224 * MB);   // 2MB
    float* lossb  = (float*)(ws + 226 * MB);   // 64KB
    float* G11 = (float*)(ws + 48 * MB);
    float* G12 = (float*)(ws + 80 * MB);
    float* G21 = (float*)(ws + 112 * MB);
    float* G22 = (float*)(ws + 144 * MB);
    float* AH  = q;     // layer AH_sem scratch
    float* AHd = kbuf;  // layer AH_dep scratch
    float* h1 = (float*)(ws + 0 * MB);
    float* h2 = (float*)(ws + 24 * MB);

    // ---- q / k projections ----
    gemm(stream, X, Wq, bq, q,    MT, D, D, D, D, D, 0, 0, 0, 0, 1, 0, 1, 0, 0);
    gemm(stream, X, Wk, bk, kbuf, MT, D, D, D, D, D, 0, 0, 0, 0, 1, 0, 1, 0, 0);

    // ---- attention -> adj_ag, in chunks of 4 batches ----
    for (int c = 0; c < 8; c++) {
        const float* qc = q    + (size_t)c * 4 * S * D;
        const float* kc = kbuf + (size_t)c * 4 * S * D;
        // scores[z= bl*8+h][s][t] = q_bh[s,:] . k_bh[t,:]   (NT, K=96)
        gemm(stream, qc, kc, nullptr, scoreC, S, S, 96, D, D, S,
             (long)S * D, 96, (long)S * D, 96, 8, (long)S * S, 32, 1, 0);
        softmax_combine<<<dim3(S, 4), 256, 0, stream>>>(scoreC, attn_mask, adj_ag, c * 4);
    }

    long nEl = (long)MT * Mm;
    int ewg = (int)((nEl + 255) / 256);

    // ---- layer 0 (H_l = X, dim D) ----
    gemm(stream, adj_ag, X, nullptr, AH, S, D, S, S, D, D,
         (long)S * S, 0, (long)S * D, 0, 1, (long)S * D, B, 0, 0);
    gemm(stream, AH, semW0, semb0, Isem, MT, Mm, D, D, Mm, Mm, 0, 0, 0, 0, 1, 0, 1, 0, 0);
    gemm(stream, adjm, X, nullptr, AHd, S, D, S, S, D, D,
         (long)S * S, 0, (long)S * D, 0, 1, (long)S * D, B, 0, 0);
    gemm(stream, AHd, depW0, depb0, Idep, MT, Mm, D, D, Mm, Mm, 0, 0, 0, 0, 1, 0, 1, 0, 0);
    gcn_combine<<<ewg, 256, 0, stream>>>(Isem, Idep, nEl);
    gemm(stream, Idep, fc3W, fc3b, Hout, MT, Mm, Mm, Mm, Mm, Mm, 0, 0, 0, 0, 1, 0, 1, 0, 1);
    gemm(stream, X, fc4W, fc4b, H, MT, Mm, D, D, Mm, Mm, 0, 0, 0, 0, 1, 0, 1, 0, 0);
    gate_combine<<<ewg, 256, 0, stream>>>(H, Hout, nEl);

    // ---- layer 1 (H_l = H, dim M) ----
    gemm(stream, adj_ag, H, nullptr, AH, S, Mm, S, S, Mm, Mm,
         (long)S * S, 0, (long)S * Mm, 0, 1, (long)S * Mm, B, 0, 0);
    gemm(stream, AH, semW1, semb1, Isem, MT, Mm, Mm, Mm, Mm, Mm, 0, 0, 0, 0, 1, 0, 1, 0, 0);
    gemm(stream, adjm, H, nullptr, AHd, S, Mm, S, S, Mm, Mm,
         (long)S * S, 0, (long)S * Mm, 0, 1, (long)S * Mm, B, 0, 0);
    gemm(stream, AHd, depW1, depb1, Idep, MT, Mm, Mm, Mm, Mm, Mm, 0, 0, 0, 0, 1, 0, 1, 0, 0);
    gcn_combine<<<ewg, 256, 0, stream>>>(Isem, Idep, nEl);
    gemm(stream, Idep, fc3W, fc3b, Hout, MT, Mm, Mm, Mm, Mm, Mm, 0, 0, 0, 0, 1, 0, 1, 0, 1);
    gate_combine<<<ewg, 256, 0, stream>>>(H, Hout, nEl);

    // ---- projection heads: h1 = proj(H), h2 = proj(Isem) ----
    gemm(stream, H, fc1W, fc1b, t1, MT, 32, Mm, Mm, 32, 32, 0, 0, 0, 0, 1, 0, 1, 0, 2);
    gemm(stream, t1, fc2W, fc2b, h1, MT, Mm, 32, 32, Mm, Mm, 0, 0, 0, 0, 1, 0, 1, 0, 0);
    gemm(stream, Isem, fc1W, fc1b, t1, MT, 32, Mm, Mm, 32, 32, 0, 0, 0, 0, 1, 0, 1, 0, 2);
    gemm(stream, t1, fc2W, fc2b, h2, MT, Mm, 32, 32, Mm, Mm, 0, 0, 0, 0, 1, 0, 1, 0, 0);

    // ---- normalize rows in place -> n1, n2 ----
    rownorm<<<dim3(MT, 2), 128, 0, stream>>>(h1, h2, Mm);

    // ---- Gram matrices (batched NT) ----
    gemm(stream, h1, h1, nullptr, G11, S, S, Mm, Mm, Mm, S,
         (long)S * Mm, 0, (long)S * Mm, 0, 1, (long)S * S, B, 1, 0);
    gemm(stream, h1, h2, nullptr, G12, S, S, Mm, Mm, Mm, S,
         (long)S * Mm, 0, (long)S * Mm, 0, 1, (long)S * S, B, 1, 0);
    gemm(stream, h2, h1, nullptr, G21, S, S, Mm, Mm, Mm, S,
         (long)S * Mm, 0, (long)S * Mm, 0, 1, (long)S * S, B, 1, 0);
    gemm(stream, h2, h2, nullptr, G22, S, S, Mm, Mm, Mm, S,
         (long)S * Mm, 0, (long)S * Mm, 0, 1, (long)S * S, B, 1, 0);

    // ---- contrastive loss + final mean ----
    loss_kernel<<<dim3(S, B), 256, 0, stream>>>(G11, G12, G21, G22, s_mask, a_mask, lossb);
    final_reduce<<<1, 256, 0, stream>>>(lossb, (float*)d_out, MT);
}

// Round 2
// 1079.442 us; speedup vs baseline: 3.4929x; 3.4929x over previous
//
#include <hip/hip_runtime.h>
#include <math.h>

// DASCO forward, round 2: all large GEMMs on bf16 MFMA (16x16x32), fp32 accum.
// B=32, S=512, D=768, M=384. Always-NT GEMM: B operands pre-cast/transposed to
// [n][k] bf16. fc1/fc2 (tiny) stay fp32. Loss math fp32.

typedef __bf16 bf16x8 __attribute__((ext_vector_type(8)));
typedef __bf16 bf16x4 __attribute__((ext_vector_type(4)));
typedef float f32x4 __attribute__((ext_vector_type(4)));

__device__ __forceinline__ void glds16(const void* g, void* l) {
    __builtin_amdgcn_global_load_lds(
        (const __attribute__((address_space(1))) unsigned*)g,
        (__attribute__((address_space(3))) unsigned*)l, 16, 0, 0);
}

// ---------------- bf16 MFMA GEMM, 128x128 tile, K%32==0, M%128==0, N%128==0 ----
// C[z][m][n] = sum_k A[z][m][k] * B[z][n][k]  (+bias[n], act) -> fp32 and/or bf16
__global__ __launch_bounds__(256) void mfma_gemm(
    const __bf16* __restrict__ A, const __bf16* __restrict__ B,
    const float* __restrict__ bias, float* __restrict__ Cf, __bf16* __restrict__ Cb,
    int K, int lda, int ldb, int ldc,
    long sAo, long sAi, long sBo, long sBi, int zInner, long sC, int act)
{
    __shared__ __bf16 As[128 * 32];
    __shared__ __bf16 Bs[128 * 32];
    int z = blockIdx.z;
    long aBase = (long)(z / zInner) * sAo + (long)(z % zInner) * sAi;
    long bBase = (long)(z / zInner) * sBo + (long)(z % zInner) * sBi;
    long cBase = (long)z * sC;
    int m0 = blockIdx.y * 128, n0 = blockIdx.x * 128;
    int tid = threadIdx.x;
    int wave = tid >> 6, lane = tid & 63;
    int wm = wave >> 1, wn = wave & 1;

    // staging: element e in [0,512): row=e>>2 (0..127), kpart=(e&3)*8
    int e0 = tid, e1 = tid + 256;
    const __bf16* Ag0 = A + aBase + (long)(m0 + (e0 >> 2)) * lda + (e0 & 3) * 8;
    const __bf16* Ag1 = A + aBase + (long)(m0 + (e1 >> 2)) * lda + (e1 & 3) * 8;
    const __bf16* Bg0 = B + bBase + (long)(n0 + (e0 >> 2)) * ldb + (e0 & 3) * 8;
    const __bf16* Bg1 = B + bBase + (long)(n0 + (e1 >> 2)) * ldb + (e1 & 3) * 8;
    __bf16* As0 = As + e0 * 8; __bf16* As1 = As + e1 * 8;
    __bf16* Bs0 = Bs + e0 * 8; __bf16* Bs1 = Bs + e1 * 8;

    f32x4 acc[4][4];
#pragma unroll
    for (int i = 0; i < 4; i++)
#pragma unroll
        for (int j = 0; j < 4; j++) acc[i][j] = (f32x4){0.f, 0.f, 0.f, 0.f};

    const bf16x8* Asv = (const bf16x8*)As;
    const bf16x8* Bsv = (const bf16x8*)Bs;
    int arow = wm * 64 + (lane & 15);   // +mi*16
    int brow = wn * 64 + (lane & 15);   // +ni*16
    int quad = lane >> 4;

    for (int k0 = 0; k0 < K; k0 += 32) {
        glds16(Ag0 + k0, As0); glds16(Ag1 + k0, As1);
        glds16(Bg0 + k0, Bs0); glds16(Bg1 + k0, Bs1);
        __syncthreads();
        bf16x8 af[4], bf[4];
#pragma unroll
        for (int mi = 0; mi < 4; mi++) af[mi] = Asv[(arow + mi * 16) * 4 + quad];
#pragma unroll
        for (int ni = 0; ni < 4; ni++) bf[ni] = Bsv[(brow + ni * 16) * 4 + quad];
#pragma unroll
        for (int mi = 0; mi < 4; mi++)
#pragma unroll
            for (int ni = 0; ni < 4; ni++)
                acc[mi][ni] = __builtin_amdgcn_mfma_f32_16x16x32_bf16(
                    af[mi], bf[ni], acc[mi][ni], 0, 0, 0);
        __syncthreads();
    }

    int crow = m0 + wm * 64 + (lane >> 4) * 4;
    int ccol = n0 + wn * 64 + (lane & 15);
    float bv[4];
#pragma unroll
    for (int ni = 0; ni < 4; ni++) bv[ni] = bias ? bias[ccol + ni * 16] : 0.f;
#pragma unroll
    for (int mi = 0; mi < 4; mi++) {
#pragma unroll
        for (int ni = 0; ni < 4; ni++) {
#pragma unroll
            for (int r = 0; r < 4; r++) {
                float v = acc[mi][ni][r] + bv[ni];
                if (act == 1) v = fmaxf(v, 0.f);
                long idx = cBase + (long)(crow + mi * 16 + r) * ldc + (ccol + ni * 16);
                if (Cf) Cf[idx] = v;
                if (Cb) Cb[idx] = (__bf16)v;
            }
        }
    }
}

// ---------------- fp32 tiled GEMM (kept for small fc1/fc2) ----------------
#define TM 64
#define TN 64
#define TK 16
__global__ __launch_bounds__(256) void gemm_kernel(
    const float* __restrict__ A, const float* __restrict__ B,
    const float* __restrict__ bias, float* __restrict__ C,
    int M, int N, int K, int lda, int ldb, int ldc, int act)
{
    __shared__ float As[TK][TM + 1];
    __shared__ float Bs[TK][TN + 1];
    int m0 = blockIdx.y * TM, n0 = blockIdx.x * TN;
    int tid = threadIdx.x;
    int tm = tid >> 4, tn = tid & 15;
    float acc[4][4];
#pragma unroll
    for (int i = 0; i < 4; i++)
#pragma unroll
        for (int j = 0; j < 4; j++) acc[i][j] = 0.f;
    int ar = tid >> 2, ac = (tid & 3) * 4;
    int bkr = tid >> 4, bnc = (tid & 15) * 4;
    for (int k0 = 0; k0 < K; k0 += TK) {
        float4 av = *(const float4*)(A + (long)(m0 + ar) * lda + (k0 + ac));
        As[ac + 0][ar] = av.x; As[ac + 1][ar] = av.y;
        As[ac + 2][ar] = av.z; As[ac + 3][ar] = av.w;
        int n = n0 + bnc;
        float4 bv = make_float4(0.f, 0.f, 0.f, 0.f);
        if (n < N) bv = *(const float4*)(B + (long)(k0 + bkr) * ldb + n);
        Bs[bkr][bnc + 0] = bv.x; Bs[bkr][bnc + 1] = bv.y;
        Bs[bkr][bnc + 2] = bv.z; Bs[bkr][bnc + 3] = bv.w;
        __syncthreads();
#pragma unroll
        for (int kk = 0; kk < TK; ++kk) {
            float a0 = As[kk][tm * 4 + 0], a1 = As[kk][tm * 4 + 1];
            float a2 = As[kk][tm * 4 + 2], a3 = As[kk][tm * 4 + 3];
            float b0 = Bs[kk][tn * 4 + 0], b1 = Bs[kk][tn * 4 + 1];
            float b2 = Bs[kk][tn * 4 + 2], b3 = Bs[kk][tn * 4 + 3];
            acc[0][0] += a0 * b0; acc[0][1] += a0 * b1; acc[0][2] += a0 * b2; acc[0][3] += a0 * b3;
            acc[1][0] += a1 * b0; acc[1][1] += a1 * b1; acc[1][2] += a1 * b2; acc[1][3] += a1 * b3;
            acc[2][0] += a2 * b0; acc[2][1] += a2 * b1; acc[2][2] += a2 * b2; acc[2][3] += a2 * b3;
            acc[3][0] += a3 * b0; acc[3][1] += a3 * b1; acc[3][2] += a3 * b2; acc[3][3] += a3 * b3;
        }
        __syncthreads();
    }
#pragma unroll
    for (int i = 0; i < 4; i++) {
        int m = m0 + tm * 4 + i;
#pragma unroll
        for (int j = 0; j < 4; j++) {
            int n = n0 + tn * 4 + j;
            if (n < N) {
                float v = acc[i][j] + (bias ? bias[n] : 0.f);
                if (act == 1) v = fmaxf(v, 0.f);
                else if (act == 2) v = (v > 0.f) ? v : expm1f(v);
                C[(long)m * ldc + n] = v;
            }
        }
    }
}

// ---------------- casts ----------------
__global__ void cast_bf16_kernel(const float* __restrict__ in, __bf16* __restrict__ out, long n4)
{
    long i = (long)blockIdx.x * blockDim.x + threadIdx.x;
    if (i < n4) {
        float4 v = ((const float4*)in)[i];
        bf16x4 o; o[0] = (__bf16)v.x; o[1] = (__bf16)v.y; o[2] = (__bf16)v.z; o[3] = (__bf16)v.w;
        ((bf16x4*)out)[i] = o;
    }
}

// fp32 [R][C] -> bf16 [C][R], batched over z (R,C multiples of 32)
__global__ __launch_bounds__(256) void castT_kernel(
    const float* __restrict__ in, __bf16* __restrict__ out, int R, int C)
{
    __shared__ float t[32][33];
    long zo = (long)blockIdx.z * R * C;
    int r0 = blockIdx.y * 32, c0 = blockIdx.x * 32;
    int tid = threadIdx.x;
    int r = tid >> 3, c4 = (tid & 7) * 4;
    float4 v = *(const float4*)(in + zo + (long)(r0 + r) * C + c0 + c4);
    t[r][c4] = v.x; t[r][c4 + 1] = v.y; t[r][c4 + 2] = v.z; t[r][c4 + 3] = v.w;
    __syncthreads();
    int c = tid >> 3, r4 = (tid & 7) * 4;
    bf16x4 o;
    o[0] = (__bf16)t[r4 + 0][c]; o[1] = (__bf16)t[r4 + 1][c];
    o[2] = (__bf16)t[r4 + 2][c]; o[3] = (__bf16)t[r4 + 3][c];
    *(bf16x4*)(out + zo + (long)(c0 + c) * R + r0 + r4) = o;
}

// ---------------- attention softmax + head-mean -> adj_ag (bf16) ----------------
__global__ __launch_bounds__(256) void softmax_combine(
    const float* __restrict__ scores, const int* __restrict__ attn_mask,
    __bf16* __restrict__ adj_agb, int b0)
{
    const int S = 512;
    int s = blockIdx.x, bl = blockIdx.y, b = b0 + bl;
    int tid = threadIdx.x;
    const float scale = 0.1020620726159658f;  // 1/sqrt(96)
    int t0 = tid, t1 = tid + 256;
    int cm0 = attn_mask[b * S + t0], cm1 = attn_mask[b * S + t1];
    float vals[8][2], part[8];
#pragma unroll
    for (int h = 0; h < 8; ++h) {
        long rb = ((long)(bl * 8 + h) * S + s) * S;
        float r0 = scores[rb + t0], r1 = scores[rb + t1];
        vals[h][0] = cm0 ? expf(r0 * scale) : 0.f;
        vals[h][1] = cm1 ? expf(r1 * scale) : 0.f;
        part[h] = vals[h][0] + vals[h][1];
    }
    __shared__ float red[4][8];
    __shared__ float linv[8];
    int lane = tid & 63, w = tid >> 6;
#pragma unroll
    for (int h = 0; h < 8; ++h) {
        float v = part[h];
        for (int o = 32; o > 0; o >>= 1) v += __shfl_down(v, o);
        if (lane == 0) red[w][h] = v;
    }
    __syncthreads();
    if (tid < 8) {
        float l = red[0][tid] + red[1][tid] + red[2][tid] + red[3][tid];
        linv[tid] = 1.f / fmaxf(l, 1e-30f);
    }
    __syncthreads();
    float rowmask = attn_mask[b * S + s] ? 1.f : 0.f;
    float a0 = 0.f, a1 = 0.f;
#pragma unroll
    for (int h = 0; h < 8; ++h) { a0 += vals[h][0] * linv[h]; a1 += vals[h][1] * linv[h]; }
    a0 *= 0.125f; a1 *= 0.125f;
    if (t0 == s) a0 = 1.f;
    if (t1 == s) a1 = 1.f;
    long ob = ((long)b * S + s) * S;
    adj_agb[ob + t0] = (__bf16)(rowmask * a0);
    adj_agb[ob + t1] = (__bf16)(rowmask * a1);
}

// ---------------- elementwise ----------------
__global__ void gcn_combine(const float* __restrict__ Isem, const float* __restrict__ Idep,
                            __bf16* __restrict__ Icomb, long n)
{
    long i = (long)blockIdx.x * blockDim.x + threadIdx.x;
    if (i < n) {
        float d = Idep[i], s = Isem[i];
        float g = 0.6f / (1.f + expf(-d));
        Icomb[i] = (__bf16)((1.f - g) * s + g * d);
    }
}

__global__ void gate_combine(float* __restrict__ H, const float* __restrict__ Hout, long n)
{
    long i = (long)blockIdx.x * blockDim.x + threadIdx.x;
    if (i < n) {
        float h = H[i];
        float g = 1.f / (1.f + expf(-h));
        H[i] = g * Hout[i] + (1.f - g) * h;
    }
}

// row L2-normalize in place + bf16 copy
__global__ __launch_bounds__(128) void rownorm(
    float* __restrict__ h1, float* __restrict__ h2,
    __bf16* __restrict__ h1b, __bf16* __restrict__ h2b, int Dm)
{
    float* p = (blockIdx.y ? h2 : h1) + (long)blockIdx.x * Dm;
    __bf16* pb = (blockIdx.y ? h2b : h1b) + (long)blockIdx.x * Dm;
    int tid = threadIdx.x;
    float ss = 0.f;
    for (int i = tid; i < Dm; i += 128) { float v = p[i]; ss += v * v; }
    for (int o = 32; o > 0; o >>= 1) ss += __shfl_down(ss, o);
    __shared__ float sb[2];
    __shared__ float scale;
    if ((tid & 63) == 0) sb[tid >> 6] = ss;
    __syncthreads();
    if (tid == 0) scale = 1.f / fmaxf(sqrtf(sb[0] + sb[1]), 1e-12f);
    __syncthreads();
    for (int i = tid; i < Dm; i += 128) {
        float v = p[i] * scale;
        p[i] = v;
        pb[i] = (__bf16)v;
    }
}

// ---------------- fused symmetric scope loss per (b,s) row ----------------
__global__ __launch_bounds__(256) void loss_kernel(
    const float* __restrict__ G11, const float* __restrict__ G12,
    const float* __restrict__ G21, const float* __restrict__ G22,
    const int* __restrict__ s_mask, const int* __restrict__ a_mask,
    float* __restrict__ lossb)
{
    const int S = 512;
    int s = blockIdx.x, b = blockIdx.y;
    long base = ((long)b * S + s) * S;
    int tid = threadIdx.x;
    const float it = 1.f / 0.07f;
    float A = a_mask[b * S + s] ? 1.f : 0.f;
    float sms = s_mask[b * S + s] ? 1.f : 0.f;
    float d12 = G12[base + s], d21 = G21[base + s];
    float w1 = A * sms * d12, w2 = A * sms * d21;
    float p[8];
#pragma unroll
    for (int h = 0; h < 8; h++) p[h] = 0.f;
#pragma unroll
    for (int j = 0; j < 2; j++) {
        int t = tid + j * 256;
        float smt = s_mask[b * S + t] ? 1.f : 0.f;
        float g11 = G11[base + t], g12 = G12[base + t];
        float g21 = G21[base + t], g22 = G22[base + t];
        if (t != s) {
            p[0] += expf(A * smt * g11 * it);
            p[1] += expf(A * smt * g12 * w1 * it);
            p[4] += expf(A * smt * g22 * it);
            p[5] += expf(A * smt * g21 * w2 * it);
        }
        p[2] += expf(A * g11 * it);
        p[3] += expf(A * g12 * it);
        p[6] += expf(A * g22 * it);
        p[7] += expf(A * g21 * it);
    }
    __shared__ float red[4][8];
    int lane = tid & 63, w = tid >> 6;
#pragma unroll
    for (int h = 0; h < 8; h++) {
        float v = p[h];
        for (int o = 32; o > 0; o >>= 1) v += __shfl_down(v, o);
        if (lane == 0) red[w][h] = v;
    }
    __syncthreads();
    if (tid == 0) {
        float r[8];
#pragma unroll
        for (int h = 0; h < 8; h++) r[h] = red[0][h] + red[1][h] + red[2][h] + red[3][h];
        float g11ss = G11[base + s], g22ss = G22[base + s];
        float pos1 = expf(w1 * it) + r[0] + r[1];
        float alle1 = r[2] - expf(A * g11ss * it) + r[3];
        float pos2 = expf(w2 * it) + r[4] + r[5];
        float alle2 = r[6] - expf(A * g22ss * it) + r[7];
        lossb[b * S + s] = 0.5f * (-logf(pos1 / alle1) - logf(pos2 / alle2));
    }
}

__global__ __launch_bounds__(256) void final_reduce(
    const float* __restrict__ lossb, float* __restrict__ out, int n)
{
    int tid = threadIdx.x;
    float s = 0.f;
    for (int i = tid; i < n; i += 256) s += lossb[i];
    for (int o = 32; o > 0; o >>= 1) s += __shfl_down(s, o);
    __shared__ float sb[4];
    if ((tid & 63) == 0) sb[tid >> 6] = s;
    __syncthreads();
    if (tid == 0) out[0] = (sb[0] + sb[1] + sb[2] + sb[3]) / (float)n;
}

// ---------------- host ----------------
static inline void mgemm(hipStream_t st, const __bf16* A, const __bf16* B, const float* bias,
                         float* Cf, __bf16* Cb, int M, int N, int K,
                         int lda, int ldb, int ldc,
                         long sAo, long sAi, long sBo, long sBi, int zInner, long sC, int nz,
                         int act)
{
    dim3 g(N / 128, M / 128, nz);
    mfma_gemm<<<g, 256, 0, st>>>(A, B, bias, Cf, Cb, K, lda, ldb, ldc,
                                 sAo, sAi, sBo, sBi, zInner, sC, act);
}

static inline void castT(hipStream_t st, const float* in, __bf16* out, int R, int C, int nz)
{
    castT_kernel<<<dim3(C / 32, R / 32, nz), 256, 0, st>>>(in, out, R, C);
}

extern "C" void kernel_launch(void* const* d_in, const int* in_sizes, int n_in,
                              void* d_out, int out_size, void* d_ws, size_t ws_size,
                              hipStream_t stream)
{
    const int B = 32, S = 512, D = 768, Mm = 384;
    const int MT = B * S;  // 16384
    const float* X    = (const float*)d_in[0];
    const float* adjm = (const float*)d_in[1];
    const int* attn_mask = (const int*)d_in[2];
    const int* s_mask    = (const int*)d_in[3];
    const int* a_mask    = (const int*)d_in[4];
    const float* Wq = (const float*)d_in[5],  *bq = (const float*)d_in[6];
    const float* Wk = (const float*)d_in[7],  *bk = (const float*)d_in[8];
    const float* semW0 = (const float*)d_in[9],  *semb0 = (const float*)d_in[10];
    const float* semW1 = (const float*)d_in[11], *semb1 = (const float*)d_in[12];
    const float* depW0 = (const float*)d_in[13], *depb0 = (const float*)d_in[14];
    const float* depW1 = (const float*)d_in[15], *depb1 = (const float*)d_in[16];
    const float* fc1W = (const float*)d_in[17], *fc1b = (const float*)d_in[18];
    const float* fc2W = (const float*)d_in[19], *fc2b = (const float*)d_in[20];
    const float* fc3W = (const float*)d_in[21], *fc3b = (const float*)d_in[22];
    const float* fc4W = (const float*)d_in[23], *fc4b = (const float*)d_in[24];

    char* ws = (char*)d_ws;
    const size_t MB = 1u << 20;
    const size_t KB = 1u << 10;
    // bf16 buffers
    __bf16* Xb     = (__bf16*)(ws + 0 * MB);            // 24MB
    __bf16* XbT    = (__bf16*)(ws + 24 * MB);           // 24MB, later HbT (12MB)
    __bf16* HbT    = (__bf16*)(ws + 24 * MB);
    __bf16* adj_agb= (__bf16*)(ws + 48 * MB);           // 16MB
    __bf16* adjmb  = (__bf16*)(ws + 64 * MB);           // 16MB, later lossb
    __bf16* qb     = (__bf16*)(ws + 80 * MB);           // 24MB, later AHb / G11
    __bf16* kb     = (__bf16*)(ws + 104 * MB);          // 24MB, later AHdb
    __bf16* AHb    = qb;
    __bf16* AHdb   = kb;
    float*  scoreC = (float*)(ws + 128 * MB);           // 32MB (attention only)
    float*  Isem   = (float*)(ws + 128 * MB);           // 24MB
    float*  Idep   = (float*)(ws + 152 * MB);           // 24MB
    float*  H      = (float*)(ws + 176 * MB);           // 24MB (written by fc4, l0)
    float*  Hout   = (float*)(ws + 200 * MB);           // 24MB (written by fc3, l0)
    // weights living in regions that are dead until mid-layer0:
    __bf16* WqT    = (__bf16*)(ws + 176 * MB);                 // 1152KB
    __bf16* WkT    = (__bf16*)(ws + 176 * MB + 1152 * KB);     // 1152KB
    __bf16* semW0T = (__bf16*)(ws + 176 * MB + 2304 * KB);     // 576KB
    __bf16* depW0T = (__bf16*)(ws + 176 * MB + 2880 * KB);     // 576KB
    __bf16* fc4WT  = (__bf16*)(ws + 200 * MB);                 // 576KB (dead before fc3 l0)
    // layer-1 weights: cast after fc4 (Xb region dead), live through fc3 l1
    __bf16* fc3WT  = (__bf16*)(ws + 12 * MB);                  // 288KB
    __bf16* semW1T = (__bf16*)(ws + 12 * MB + 288 * KB);       // 288KB
    __bf16* depW1T = (__bf16*)(ws + 12 * MB + 576 * KB);       // 288KB
    __bf16* Icomb  = (__bf16*)(ws + 0 * MB);                   // 12MB (Xb dead)
    // phase C
    float*  t1   = (float*)(ws + 0 * MB);              // 2MB
    __bf16* h1b  = (__bf16*)(ws + 8 * MB);             // 12MB
    __bf16* h2b  = (__bf16*)(ws + 20 * MB);            // 12MB
    float*  G22  = (float*)(ws + 32 * MB);             // 32MB
    float*  lossb= (float*)(ws + 64 * MB);             // 64KB
    float*  G11  = (float*)(ws + 80 * MB);             // 32MB
    float*  G12  = (float*)(ws + 112 * MB);            // 32MB
    float*  G21  = (float*)(ws + 144 * MB);            // 32MB
    float*  h1   = (float*)(ws + 176 * MB);            // 24MB (H dead after fc1)
    float*  h2   = (float*)(ws + 200 * MB);            // 24MB (Hout dead)

    long nEl = (long)MT * Mm;
    int ewg = (int)((nEl + 255) / 256);

    // ---- phase 0: casts ----
    cast_bf16_kernel<<<(MT * D / 4 + 255) / 256, 256, 0, stream>>>(X, Xb, (long)MT * D / 4);
    cast_bf16_kernel<<<((long)B * S * S / 4 + 255) / 256, 256, 0, stream>>>(adjm, adjmb, (long)B * S * S / 4);
    castT(stream, X, XbT, S, D, B);          // per-batch [768][512]
    castT(stream, Wq, WqT, D, D, 1);
    castT(stream, Wk, WkT, D, D, 1);
    castT(stream, semW0, semW0T, D, Mm, 1);
    castT(stream, depW0, depW0T, D, Mm, 1);
    castT(stream, fc4W, fc4WT, D, Mm, 1);

    // ---- q/k projections (bf16 out) ----
    mgemm(stream, Xb, WqT, bq, nullptr, qb, MT, D, D, D, D, D, 0, 0, 0, 0, 1, 0, 1, 0);
    mgemm(stream, Xb, WkT, bk, nullptr, kb, MT, D, D, D, D, D, 0, 0, 0, 0, 1, 0, 1, 0);

    // ---- attention -> adj_agb, chunks of 4 batches ----
    for (int c = 0; c < 8; c++) {
        const __bf16* qc = qb + (size_t)c * 4 * S * D;
        const __bf16* kc = kb + (size_t)c * 4 * S * D;
        mgemm(stream, qc, kc, nullptr, scoreC, nullptr, S, S, 96, D, D, S,
              (long)S * D, 96, (long)S * D, 96, 8, (long)S * S, 32, 0);
        softmax_combine<<<dim3(S, 4), 256, 0, stream>>>(scoreC, attn_mask, adj_agb, c * 4);
    }

    // ---- layer 0 ----
    mgemm(stream, adj_agb, XbT, nullptr, nullptr, AHb, S, D, S, S, S, D,
          (long)S * S, 0, (long)D * S, 0, 1, (long)S * D, B, 0);
    mgemm(stream, AHb, semW0T, semb0, Isem, nullptr, MT, Mm, D, D, D, Mm, 0, 0, 0, 0, 1, 0, 1, 0);
    mgemm(stream, adjmb, XbT, nullptr, nullptr, AHdb, S, D, S, S, S, D,
          (long)S * S, 0, (long)D * S, 0, 1, (long)S * D, B, 0);
    mgemm(stream, AHdb, depW0T, depb0, Idep, nullptr, MT, Mm, D, D, D, Mm, 0, 0, 0, 0, 1, 0, 1, 0);
    mgemm(stream, Xb, fc4WT, fc4b, H, nullptr, MT, Mm, D, D, D, Mm, 0, 0, 0, 0, 1, 0, 1, 0);
    // Xb now dead: cast layer-1 weights into its region
    castT(stream, fc3W, fc3WT, Mm, Mm, 1);
    castT(stream, semW1, semW1T, Mm, Mm, 1);
    castT(stream, depW1, depW1T, Mm, Mm, 1);
    gcn_combine<<<ewg, 256, 0, stream>>>(Isem, Idep, Icomb, nEl);
    mgemm(stream, Icomb, fc3WT, fc3b, Hout, nullptr, MT, Mm, Mm, Mm, Mm, Mm, 0, 0, 0, 0, 1, 0, 1, 1);
    gate_combine<<<ewg, 256, 0, stream>>>(H, Hout, nEl);

    // ---- layer 1 ----
    castT(stream, H, HbT, S, Mm, B);   // per-batch [384][512]
    mgemm(stream, adj_agb, HbT, nullptr, nullptr, AHb, S, Mm, S, S, S, Mm,
          (long)S * S, 0, (long)Mm * S, 0, 1, (long)S * Mm, B, 0);
    mgemm(stream, AHb, semW1T, semb1, Isem, nullptr, MT, Mm, Mm, Mm, Mm, Mm, 0, 0, 0, 0, 1, 0, 1, 0);
    mgemm(stream, adjmb, HbT, nullptr, nullptr, AHdb, S, Mm, S, S, S, Mm,
          (long)S * S, 0, (long)Mm * S, 0, 1, (long)S * Mm, B, 0);
    mgemm(stream, AHdb, depW1T, depb1, Idep, nullptr, MT, Mm, Mm, Mm, Mm, Mm, 0, 0, 0, 0, 1, 0, 1, 0);
    gcn_combine<<<ewg, 256, 0, stream>>>(Isem, Idep, Icomb, nEl);
    mgemm(stream, Icomb, fc3WT, fc3b, Hout, nullptr, MT, Mm, Mm, Mm, Mm, Mm, 0, 0, 0, 0, 1, 0, 1, 1);
    gate_combine<<<ewg, 256, 0, stream>>>(H, Hout, nEl);

    // ---- projection heads (fp32 small gemms) ----
    {
        dim3 g1(1, MT / TM), g2((Mm + TN - 1) / TN, MT / TM);
        gemm_kernel<<<g1, 256, 0, stream>>>(H, fc1W, fc1b, t1, MT, 32, Mm, Mm, 32, 32, 2);
        gemm_kernel<<<g2, 256, 0, stream>>>(t1, fc2W, fc2b, h1, MT, Mm, 32, 32, Mm, Mm, 0);
        gemm_kernel<<<g1, 256, 0, stream>>>(Isem, fc1W, fc1b, t1, MT, 32, Mm, Mm, 32, 32, 2);
        gemm_kernel<<<g2, 256, 0, stream>>>(t1, fc2W, fc2b, h2, MT, Mm, 32, 32, Mm, Mm, 0);
    }

    rownorm<<<dim3(MT, 2), 128, 0, stream>>>(h1, h2, h1b, h2b, Mm);

    // ---- Gram matrices (bf16 MFMA, NT) ----
    mgemm(stream, h1b, h1b, nullptr, G11, nullptr, S, S, Mm, Mm, Mm, S,
          (long)S * Mm, 0, (long)S * Mm, 0, 1, (long)S * S, B, 0);
    mgemm(stream, h1b, h2b, nullptr, G12, nullptr, S, S, Mm, Mm, Mm, S,
          (long)S * Mm, 0, (long)S * Mm, 0, 1, (long)S * S, B, 0);
    mgemm(stream, h2b, h1b, nullptr, G21, nullptr, S, S, Mm, Mm, Mm, S,
          (long)S * Mm, 0, (long)S * Mm, 0, 1, (long)S * S, B, 0);
    mgemm(stream, h2b, h2b, nullptr, G22, nullptr, S, S, Mm, Mm, Mm, S,
          (long)S * Mm, 0, (long)S * Mm, 0, 1, (long)S * S, B, 0);

    // ---- loss ----
    loss_kernel<<<dim3(S, B), 256, 0, stream>>>(G11, G12, G21, G22, s_mask, a_mask, lossb);
    final_reduce<<<1, 256, 0, stream>>>(lossb, (float*)d_out, MT);
}

// Round 3
// 1051.333 us; speedup vs baseline: 3.5863x; 1.0267x over previous
//
#include <hip/hip_runtime.h>
#include <math.h>

// DASCO forward, round 3: bf16 MFMA everywhere (incl. fc1/fc2), fused epilogues
// (gcn-combine, gate), bf16 scores, merged dispatches, fast-exp loss with
// a_mask early-exit. B=32, S=512, D=768, M=384.

typedef __bf16 bf16x8 __attribute__((ext_vector_type(8)));
typedef __bf16 bf16x4 __attribute__((ext_vector_type(4)));
typedef float f32x4 __attribute__((ext_vector_type(4)));

__device__ __forceinline__ void glds16(const void* g, void* l) {
    __builtin_amdgcn_global_load_lds(
        (const __attribute__((address_space(1))) unsigned*)g,
        (__attribute__((address_space(3))) unsigned*)l, 16, 0, 0);
}

__device__ __forceinline__ float sigf(float x) { return 1.f / (1.f + __expf(-x)); }

// ---------------- bf16 MFMA GEMM, 128x128 tile, K%32==0, M%128==0, Npad%128==0 --
// C[z][m][n] = sum_k A[z][m][k]*B[z][n][k] (+bias), epilogue act:
// 0 none; 1 relu; 2 elu; 3 gcn-combine(E=Isem); 4 relu+gate(E=Hold)
// writes masked to n < nMax. Cf fp32 and/or Cb bf16 outputs.
__global__ __launch_bounds__(256) void mfma_gemm(
    const __bf16* __restrict__ A, const __bf16* __restrict__ B,
    const float* __restrict__ bias, const float* __restrict__ E,
    float* __restrict__ Cf, __bf16* __restrict__ Cb,
    int K, int lda, int ldb, int ldc, int nMax,
    long sAo, long sAi, long sBo, long sBi, int zInner, long sC, int act)
{
    __shared__ __bf16 As[128 * 32];
    __shared__ __bf16 Bs[128 * 32];
    int z = blockIdx.z;
    long aBase = (long)(z / zInner) * sAo + (long)(z % zInner) * sAi;
    long bBase = (long)(z / zInner) * sBo + (long)(z % zInner) * sBi;
    long cBase = (long)z * sC;
    int m0 = blockIdx.y * 128, n0 = blockIdx.x * 128;
    int tid = threadIdx.x;
    int wave = tid >> 6, lane = tid & 63;
    int wm = wave >> 1, wn = wave & 1;

    int e0 = tid, e1 = tid + 256;
    const __bf16* Ag0 = A + aBase + (long)(m0 + (e0 >> 2)) * lda + (e0 & 3) * 8;
    const __bf16* Ag1 = A + aBase + (long)(m0 + (e1 >> 2)) * lda + (e1 & 3) * 8;
    const __bf16* Bg0 = B + bBase + (long)(n0 + (e0 >> 2)) * ldb + (e0 & 3) * 8;
    const __bf16* Bg1 = B + bBase + (long)(n0 + (e1 >> 2)) * ldb + (e1 & 3) * 8;
    __bf16* As0 = As + e0 * 8; __bf16* As1 = As + e1 * 8;
    __bf16* Bs0 = Bs + e0 * 8; __bf16* Bs1 = Bs + e1 * 8;

    f32x4 acc[4][4];
#pragma unroll
    for (int i = 0; i < 4; i++)
#pragma unroll
        for (int j = 0; j < 4; j++) acc[i][j] = (f32x4){0.f, 0.f, 0.f, 0.f};

    const bf16x8* Asv = (const bf16x8*)As;
    const bf16x8* Bsv = (const bf16x8*)Bs;
    int arow = wm * 64 + (lane & 15);
    int brow = wn * 64 + (lane & 15);
    int quad = lane >> 4;

    for (int k0 = 0; k0 < K; k0 += 32) {
        glds16(Ag0 + k0, As0); glds16(Ag1 + k0, As1);
        glds16(Bg0 + k0, Bs0); glds16(Bg1 + k0, Bs1);
        __syncthreads();
        bf16x8 af[4], bfr[4];
#pragma unroll
        for (int mi = 0; mi < 4; mi++) af[mi] = Asv[(arow + mi * 16) * 4 + quad];
#pragma unroll
        for (int ni = 0; ni < 4; ni++) bfr[ni] = Bsv[(brow + ni * 16) * 4 + quad];
#pragma unroll
        for (int mi = 0; mi < 4; mi++)
#pragma unroll
            for (int ni = 0; ni < 4; ni++)
                acc[mi][ni] = __builtin_amdgcn_mfma_f32_16x16x32_bf16(
                    af[mi], bfr[ni], acc[mi][ni], 0, 0, 0);
        __syncthreads();
    }

    int crow = m0 + wm * 64 + (lane >> 4) * 4;
    int ccol = n0 + wn * 64 + (lane & 15);
    float bv[4];
#pragma unroll
    for (int ni = 0; ni < 4; ni++) {
        int col = ccol + ni * 16;
        bv[ni] = (bias && col < nMax) ? bias[col] : 0.f;
    }
#pragma unroll
    for (int mi = 0; mi < 4; mi++) {
#pragma unroll
        for (int ni = 0; ni < 4; ni++) {
            int col = ccol + ni * 16;
            if (col >= nMax) continue;
#pragma unroll
            for (int r = 0; r < 4; r++) {
                float v = acc[mi][ni][r] + bv[ni];
                long idx = cBase + (long)(crow + mi * 16 + r) * ldc + col;
                if (act == 1) v = fmaxf(v, 0.f);
                else if (act == 2) v = (v > 0.f) ? v : expm1f(v);
                else if (act == 3) { float e = E[idx]; float g = 0.6f * sigf(v); v = (1.f - g) * e + g * v; }
                else if (act == 4) { float e = E[idx]; v = fmaxf(v, 0.f); float g = sigf(e); v = g * v + (1.f - g) * e; }
                if (Cf) Cf[idx] = v;
                if (Cb) Cb[idx] = (__bf16)v;
            }
        }
    }
}

// ---------------- casts ----------------
__global__ void cast_bf16_kernel(const float* __restrict__ in, __bf16* __restrict__ out, long n4)
{
    long i = (long)blockIdx.x * blockDim.x + threadIdx.x;
    if (i < n4) {
        float4 v = ((const float4*)in)[i];
        bf16x4 o; o[0] = (__bf16)v.x; o[1] = (__bf16)v.y; o[2] = (__bf16)v.z; o[3] = (__bf16)v.w;
        ((bf16x4*)out)[i] = o;
    }
}

// fp32 [R][C] -> bf16 [C][R], batched over z (R,C multiples of 32)
__global__ __launch_bounds__(256) void castT_kernel(
    const float* __restrict__ in, __bf16* __restrict__ out, int R, int C)
{
    __shared__ float t[32][33];
    long zo = (long)blockIdx.z * R * C;
    int r0 = blockIdx.y * 32, c0 = blockIdx.x * 32;
    int tid = threadIdx.x;
    int r = tid >> 3, c4 = (tid & 7) * 4;
    float4 v = *(const float4*)(in + zo + (long)(r0 + r) * C + c0 + c4);
    t[r][c4] = v.x; t[r][c4 + 1] = v.y; t[r][c4 + 2] = v.z; t[r][c4 + 3] = v.w;
    __syncthreads();
    int c = tid >> 3, r4 = (tid & 7) * 4;
    bf16x4 o;
    o[0] = (__bf16)t[r4 + 0][c]; o[1] = (__bf16)t[r4 + 1][c];
    o[2] = (__bf16)t[r4 + 2][c]; o[3] = (__bf16)t[r4 + 3][c];
    *(bf16x4*)(out + zo + (long)(c0 + c) * R + r0 + r4) = o;
}

// ---------------- attention softmax + head-mean -> adj_ag (bf16 in/out) -------
__global__ __launch_bounds__(256) void softmax_combine(
    const __bf16* __restrict__ scores, const int* __restrict__ attn_mask,
    __bf16* __restrict__ adj_agb, int b0)
{
    const int S = 512;
    int s = blockIdx.x, bl = blockIdx.y, b = b0 + bl;
    int tid = threadIdx.x;
    const float scale = 0.1020620726159658f;  // 1/sqrt(96)
    int t0 = tid, t1 = tid + 256;
    int cm0 = attn_mask[b * S + t0], cm1 = attn_mask[b * S + t1];
    float vals[8][2], part[8];
#pragma unroll
    for (int h = 0; h < 8; ++h) {
        long rb = ((long)(bl * 8 + h) * S + s) * S;
        float r0 = (float)scores[rb + t0], r1 = (float)scores[rb + t1];
        vals[h][0] = cm0 ? __expf(r0 * scale) : 0.f;
        vals[h][1] = cm1 ? __expf(r1 * scale) : 0.f;
        part[h] = vals[h][0] + vals[h][1];
    }
    __shared__ float red[4][8];
    __shared__ float linv[8];
    int lane = tid & 63, w = tid >> 6;
#pragma unroll
    for (int h = 0; h < 8; ++h) {
        float v = part[h];
        for (int o = 32; o > 0; o >>= 1) v += __shfl_down(v, o);
        if (lane == 0) red[w][h] = v;
    }
    __syncthreads();
    if (tid < 8) {
        float l = red[0][tid] + red[1][tid] + red[2][tid] + red[3][tid];
        linv[tid] = 1.f / fmaxf(l, 1e-30f);
    }
    __syncthreads();
    float rowmask = attn_mask[b * S + s] ? 1.f : 0.f;
    float a0 = 0.f, a1 = 0.f;
#pragma unroll
    for (int h = 0; h < 8; ++h) { a0 += vals[h][0] * linv[h]; a1 += vals[h][1] * linv[h]; }
    a0 *= 0.125f; a1 *= 0.125f;
    if (t0 == s) a0 = 1.f;
    if (t1 == s) a1 = 1.f;
    long ob = ((long)b * S + s) * S;
    adj_agb[ob + t0] = (__bf16)(rowmask * a0);
    adj_agb[ob + t1] = (__bf16)(rowmask * a1);
}

// ---------------- row L2-normalize in place + bf16 copy ----------------
__global__ __launch_bounds__(128) void rownorm(
    float* __restrict__ h1, float* __restrict__ h2,
    __bf16* __restrict__ h1b, __bf16* __restrict__ h2b, int Dm)
{
    float* p = (blockIdx.y ? h2 : h1) + (long)blockIdx.x * Dm;
    __bf16* pb = (blockIdx.y ? h2b : h1b) + (long)blockIdx.x * Dm;
    int tid = threadIdx.x;
    float ss = 0.f;
    for (int i = tid; i < Dm; i += 128) { float v = p[i]; ss += v * v; }
    for (int o = 32; o > 0; o >>= 1) ss += __shfl_down(ss, o);
    __shared__ float sb[2];
    __shared__ float scale;
    if ((tid & 63) == 0) sb[tid >> 6] = ss;
    __syncthreads();
    if (tid == 0) scale = 1.f / fmaxf(sqrtf(sb[0] + sb[1]), 1e-12f);
    __syncthreads();
    for (int i = tid; i < Dm; i += 128) {
        float v = p[i] * scale;
        pb[i] = (__bf16)v;
    }
}

// ---------------- fused symmetric scope loss per (b,s) row ----------------
// a_mask==0 rows: all masked sims are 0 -> pos==alle -> loss 0 (early exit).
__global__ __launch_bounds__(256) void loss_kernel(
    const float* __restrict__ G11, const float* __restrict__ G12,
    const float* __restrict__ G21, const float* __restrict__ G22,
    const int* __restrict__ s_mask, const int* __restrict__ a_mask,
    float* __restrict__ lossb)
{
    const int S = 512;
    int s = blockIdx.x, b = blockIdx.y;
    int tid = threadIdx.x;
    if (a_mask[b * S + s] == 0) {
        if (tid == 0) lossb[b * S + s] = 0.f;
        return;
    }
    long base = ((long)b * S + s) * S;
    const float it = 1.f / 0.07f;
    float sms = s_mask[b * S + s] ? 1.f : 0.f;
    float d12 = G12[base + s], d21 = G21[base + s];
    float w1 = sms * d12, w2 = sms * d21;
    float w1i = w1 * it, w2i = w2 * it;
    float p[8];
#pragma unroll
    for (int h = 0; h < 8; h++) p[h] = 0.f;
#pragma unroll
    for (int j = 0; j < 2; j++) {
        int t = tid + j * 256;
        bool smt = s_mask[b * S + t] != 0;
        bool off = (t != s);
        float g11 = G11[base + t], g12 = G12[base + t];
        float g21 = G21[base + t], g22 = G22[base + t];
        float e11 = __expf(g11 * it), e12 = __expf(g12 * it);
        float e21 = __expf(g21 * it), e22 = __expf(g22 * it);
        p[2] += e11; p[3] += e12; p[6] += e22; p[7] += e21;
        if (off) {
            p[0] += smt ? e11 : 1.f;
            p[4] += smt ? e22 : 1.f;
            p[1] += smt ? __expf(g12 * w1i) : 1.f;
            p[5] += smt ? __expf(g21 * w2i) : 1.f;
        }
    }
    __shared__ float red[4][8];
    int lane = tid & 63, w = tid >> 6;
#pragma unroll
    for (int h = 0; h < 8; h++) {
        float v = p[h];
        for (int o = 32; o > 0; o >>= 1) v += __shfl_down(v, o);
        if (lane == 0) red[w][h] = v;
    }
    __syncthreads();
    if (tid == 0) {
        float r[8];
#pragma unroll
        for (int h = 0; h < 8; h++) r[h] = red[0][h] + red[1][h] + red[2][h] + red[3][h];
        float g11ss = G11[base + s], g22ss = G22[base + s];
        float pos1 = __expf(w1i) + r[0] + r[1];
        float alle1 = r[2] - __expf(g11ss * it) + r[3];
        float pos2 = __expf(w2i) + r[4] + r[5];
        float alle2 = r[6] - __expf(g22ss * it) + r[7];
        lossb[b * S + s] = 0.5f * ((__logf(alle1) - __logf(pos1)) +
                                   (__logf(alle2) - __logf(pos2)));
    }
}

__global__ __launch_bounds__(256) void final_reduce(
    const float* __restrict__ lossb, float* __restrict__ out, int n)
{
    int tid = threadIdx.x;
    float s = 0.f;
    for (int i = tid; i < n; i += 256) s += lossb[i];
    for (int o = 32; o > 0; o >>= 1) s += __shfl_down(s, o);
    __shared__ float sb[4];
    if ((tid & 63) == 0) sb[tid >> 6] = s;
    __syncthreads();
    if (tid == 0) out[0] = (sb[0] + sb[1] + sb[2] + sb[3]) / (float)n;
}

// ---------------- host ----------------
static inline void mg(hipStream_t st, const __bf16* A, const __bf16* B, const float* bias,
                      const float* E, float* Cf, __bf16* Cb,
                      int M, int Npad, int nMax, int K, int lda, int ldb, int ldc,
                      long sAo, long sAi, long sBo, long sBi, int zInner, long sC, int nz,
                      int act)
{
    dim3 g(Npad / 128, M / 128, nz);
    mfma_gemm<<<g, 256, 0, st>>>(A, B, bias, E, Cf, Cb, K, lda, ldb, ldc, nMax,
                                 sAo, sAi, sBo, sBi, zInner, sC, act);
}

static inline void castT(hipStream_t st, const float* in, __bf16* out, int R, int C, int nz)
{
    castT_kernel<<<dim3(C / 32, R / 32, nz), 256, 0, st>>>(in, out, R, C);
}

extern "C" void kernel_launch(void* const* d_in, const int* in_sizes, int n_in,
                              void* d_out, int out_size, void* d_ws, size_t ws_size,
                              hipStream_t stream)
{
    const int B = 32, S = 512, D = 768, Mm = 384;
    const int MT = B * S;  // 16384
    const float* X    = (const float*)d_in[0];
    const float* adjm = (const float*)d_in[1];
    const int* attn_mask = (const int*)d_in[2];
    const int* s_mask    = (const int*)d_in[3];
    const int* a_mask    = (const int*)d_in[4];
    const float* Wq = (const float*)d_in[5],  *bq = (const float*)d_in[6];
    const float* Wk = (const float*)d_in[7],  *bk = (const float*)d_in[8];
    const float* semW0 = (const float*)d_in[9],  *semb0 = (const float*)d_in[10];
    const float* semW1 = (const float*)d_in[11], *semb1 = (const float*)d_in[12];
    const float* depW0 = (const float*)d_in[13], *depb0 = (const float*)d_in[14];
    const float* depW1 = (const float*)d_in[15], *depb1 = (const float*)d_in[16];
    const float* fc1W = (const float*)d_in[17], *fc1b = (const float*)d_in[18];
    const float* fc2W = (const float*)d_in[19], *fc2b = (const float*)d_in[20];
    const float* fc3W = (const float*)d_in[21], *fc3b = (const float*)d_in[22];
    const float* fc4W = (const float*)d_in[23], *fc4b = (const float*)d_in[24];

    char* ws = (char*)d_ws;
    const size_t MB = 1u << 20;
    const size_t KB = 1u << 10;

    // ---- main rotating regions (byte offsets; see liveness notes) ----
    __bf16* Xb      = (__bf16*)(ws + 0 * MB);     // 24MB
    __bf16* XbT     = (__bf16*)(ws + 24 * MB);    // 24MB
    __bf16* HbT     = (__bf16*)(ws + 24 * MB);    // 12MB (layer1, XbT dead)
    __bf16* adj_agb = (__bf16*)(ws + 48 * MB);    // 16MB  \ contiguous pair
    __bf16* adjmb   = (__bf16*)(ws + 64 * MB);    // 16MB  /
    __bf16* qkb     = (__bf16*)(ws + 80 * MB);    // 48MB [16384][1536]
    __bf16* AH64    = (__bf16*)(ws + 80 * MB);    // 48MB (l0: 64 slices S*D)
    __bf16* AH64b   = (__bf16*)(ws + 80 * MB);    // 24MB (l1: 64 slices S*M)
    __bf16* Isemb   = (__bf16*)(ws + 104 * MB);   // 12MB (l1)
    __bf16* Hb      = (__bf16*)(ws + 116 * MB);   // 12MB (l1)
    __bf16* scoreB  = (__bf16*)(ws + 128 * MB);   // 32MB (attention chunks)
    float*  Isem    = (float*)(ws + 128 * MB);    // 24MB (layers)
    __bf16* Icomb   = (__bf16*)(ws + 152 * MB);   // 12MB
    float*  H       = (float*)(ws + 164 * MB);    // 24MB
    __bf16* t1b     = (__bf16*)(ws + 0 * MB);     // 1MB (proj, Xb dead)
    float*  h1      = (float*)(ws + 4 * MB);      // 24MB
    float*  h2      = (float*)(ws + 28 * MB);     // 24MB
    __bf16* h1b     = (__bf16*)(ws + 52 * MB);    // 12MB \ contiguous pair
    __bf16* h2b     = (__bf16*)(ws + 64 * MB);    // 12MB /
    float*  G11     = (float*)(ws + 80 * MB);     // 32MB
    float*  G12     = (float*)(ws + 112 * MB);    // 32MB
    float*  G21     = (float*)(ws + 144 * MB);    // 32MB
    float*  G22     = (float*)(ws + 176 * MB);    // 32MB (ends 208MB)

    // ---- permanent weight region @209MB ----
    char* wreg = ws + 209 * MB;
    __bf16* WqkT   = (__bf16*)(wreg + 0 * KB);     // [1536][768] 2304KB
    __bf16* semW0T = (__bf16*)(wreg + 2304 * KB);  // [384][768] 576KB
    __bf16* depW0T = (__bf16*)(wreg + 2880 * KB);  // 576KB
    __bf16* fc4WT  = (__bf16*)(wreg + 3456 * KB);  // 576KB
    __bf16* fc3WT  = (__bf16*)(wreg + 4032 * KB);  // [384][384] 288KB
    __bf16* semW1T = (__bf16*)(wreg + 4320 * KB);  // 288KB
    __bf16* depW1T = (__bf16*)(wreg + 4608 * KB);  // 288KB
    __bf16* fc1WT  = (__bf16*)(wreg + 4896 * KB);  // [128 pad][384] 96KB
    __bf16* fc2WT  = (__bf16*)(wreg + 4992 * KB);  // [384][32] 24KB
    float*  bqk    = (float*)(wreg + 5016 * KB);   // [1536] 6KB
    float*  lossb  = (float*)(wreg + 5024 * KB);   // 64KB

    long nSD = (long)S * D, nSM = (long)S * Mm, nSS = (long)S * S;

    // ---- weight casts (all independent, run first) ----
    cast_bf16_kernel<<<(MT * D / 4 + 255) / 256, 256, 0, stream>>>(X, Xb, (long)MT * D / 4);
    cast_bf16_kernel<<<((long)B * nSS / 4 + 255) / 256, 256, 0, stream>>>(adjm, adjmb, (long)B * nSS / 4);
    castT(stream, X, XbT, S, D, B);
    castT(stream, Wq, WqkT, D, D, 1);
    castT(stream, Wk, WqkT + (long)D * D, D, D, 1);
    castT(stream, semW0, semW0T, D, Mm, 1);
    castT(stream, depW0, depW0T, D, Mm, 1);
    castT(stream, fc4W, fc4WT, D, Mm, 1);
    castT(stream, fc3W, fc3WT, Mm, Mm, 1);
    castT(stream, semW1, semW1T, Mm, Mm, 1);
    castT(stream, depW1, depW1T, Mm, Mm, 1);
    castT(stream, fc1W, fc1WT, Mm, 32, 1);
    hipMemsetAsync(fc1WT + 32 * Mm, 0, (size_t)96 * Mm * 2, stream);  // pad rows
    castT(stream, fc2W, fc2WT, 32, Mm, 1);
    hipMemcpyAsync(bqk, bq, D * 4, hipMemcpyDeviceToDevice, stream);
    hipMemcpyAsync(bqk + D, bk, D * 4, hipMemcpyDeviceToDevice, stream);

    // ---- fused q|k projection: [16384][1536] bf16 ----
    mg(stream, Xb, WqkT, bqk, nullptr, nullptr, qkb, MT, 1536, 1536, D,
       D, D, 1536, 0, 0, 0, 0, 1, 0, 1, 0);

    // ---- attention scores (bf16) + softmax/head-mean, 4 chunks of 8 batches --
    for (int c = 0; c < 4; c++) {
        const __bf16* qc = qkb + (long)c * 8 * S * 1536;
        mg(stream, qc, qc + 768, nullptr, nullptr, nullptr, scoreB, S, S, S, 96,
           1536, 1536, S, (long)S * 1536, 96, (long)S * 1536, 96, 8, nSS, 64, 0);
        softmax_combine<<<dim3(S, 8), 256, 0, stream>>>(scoreB, attn_mask, adj_agb, c * 8);
    }

    // ---- layer 0: merged adjacency GEMM (z<32: adj_ag, z>=32: adjm) ----
    mg(stream, adj_agb, XbT, nullptr, nullptr, nullptr, AH64, S, D, D, S,
       S, S, D, 32 * nSS, nSS, 0, nSD, 32, nSD, 64, 0);
    mg(stream, AH64, semW0T, semb0, nullptr, Isem, nullptr, MT, Mm, Mm, D,
       D, D, Mm, 0, 0, 0, 0, 1, 0, 1, 0);
    mg(stream, AH64 + 32 * nSD, depW0T, depb0, Isem, nullptr, Icomb, MT, Mm, Mm, D,
       D, D, Mm, 0, 0, 0, 0, 1, 0, 1, 3);
    mg(stream, Xb, fc4WT, fc4b, nullptr, H, nullptr, MT, Mm, Mm, D,
       D, D, Mm, 0, 0, 0, 0, 1, 0, 1, 0);
    mg(stream, Icomb, fc3WT, fc3b, H, H, nullptr, MT, Mm, Mm, Mm,
       Mm, Mm, Mm, 0, 0, 0, 0, 1, 0, 1, 4);   // relu + gate, H in-place

    // ---- layer 1 ----
    castT(stream, H, HbT, S, Mm, B);
    mg(stream, adj_agb, HbT, nullptr, nullptr, nullptr, AH64b, S, Mm, Mm, S,
       S, S, Mm, 32 * nSS, nSS, 0, nSM, 32, nSM, 64, 0);
    mg(stream, AH64b, semW1T, semb1, nullptr, Isem, Isemb, MT, Mm, Mm, Mm,
       Mm, Mm, Mm, 0, 0, 0, 0, 1, 0, 1, 0);
    mg(stream, AH64b + 32 * nSM, depW1T, depb1, Isem, nullptr, Icomb, MT, Mm, Mm, Mm,
       Mm, Mm, Mm, 0, 0, 0, 0, 1, 0, 1, 3);
    mg(stream, Icomb, fc3WT, fc3b, H, H, Hb, MT, Mm, Mm, Mm,
       Mm, Mm, Mm, 0, 0, 0, 0, 1, 0, 1, 4);

    // ---- projection heads (MFMA, fc1 N padded 128->mask 32) ----
    mg(stream, Hb, fc1WT, fc1b, nullptr, nullptr, t1b, MT, 128, 32, Mm,
       Mm, Mm, 32, 0, 0, 0, 0, 1, 0, 1, 2);
    mg(stream, t1b, fc2WT, fc2b, nullptr, h1, nullptr, MT, Mm, Mm, 32,
       32, 32, Mm, 0, 0, 0, 0, 1, 0, 1, 0);
    mg(stream, Isemb, fc1WT, fc1b, nullptr, nullptr, t1b, MT, 128, 32, Mm,
       Mm, Mm, 32, 0, 0, 0, 0, 1, 0, 1, 2);
    mg(stream, t1b, fc2WT, fc2b, nullptr, h2, nullptr, MT, Mm, Mm, 32,
       32, 32, Mm, 0, 0, 0, 0, 1, 0, 1, 0);

    rownorm<<<dim3(MT, 2), 128, 0, stream>>>(h1, h2, h1b, h2b, Mm);

    // ---- Gram matrices: 2 merged dispatches (z<32: B=h1b, z>=32: B=h2b) ----
    long sB2 = 6291456;  // 12MB in bf16 elements
    mg(stream, h1b, h1b, nullptr, nullptr, G11, nullptr, S, S, S, Mm,
       Mm, Mm, S, 0, nSM, sB2, nSM, 32, nSS, 64, 0);   // -> G11 | G12
    mg(stream, h2b, h1b, nullptr, nullptr, G21, nullptr, S, S, S, Mm,
       Mm, Mm, S, 0, nSM, sB2, nSM, 32, nSS, 64, 0);   // -> G21 | G22

    // ---- loss ----
    loss_kernel<<<dim3(S, B), 256, 0, stream>>>(G11, G12, G21, G22, s_mask, a_mask, lossb);
    final_reduce<<<1, 256, 0, stream>>>(lossb, (float*)d_out, MT);
}

// Round 4
// 948.508 us; speedup vs baseline: 3.9751x; 1.1084x over previous
//
#include <hip/hip_runtime.h>
#include <math.h>

// DASCO forward, round 4: reassociated GCN layers (adj@(H@W) instead of
// (adj@H)@W) -> no big adjacency-x-features GEMM, no transposed-activation
// casts; bf16 Gram matrices; merged score chunks. B=32, S=512, D=768, M=384.

typedef __bf16 bf16x8 __attribute__((ext_vector_type(8)));
typedef __bf16 bf16x4 __attribute__((ext_vector_type(4)));
typedef float f32x4 __attribute__((ext_vector_type(4)));

__device__ __forceinline__ void glds16(const void* g, void* l) {
    __builtin_amdgcn_global_load_lds(
        (const __attribute__((address_space(1))) unsigned*)g,
        (__attribute__((address_space(3))) unsigned*)l, 16, 0, 0);
}

__device__ __forceinline__ float sigf(float x) { return 1.f / (1.f + __expf(-x)); }

// ---------------- bf16 MFMA GEMM, 128x128 tile, K%32==0, M%128==0, Npad%128==0 --
// C[z][m][n] = sum_k A[z][m][k]*B[z][n][k] (+bias), epilogue act:
// 0 none; 1 relu; 2 elu; 3 gcn-combine(E=Isem); 4 relu+gate(E=Hold)
// writes masked to n < nMax. Cf fp32 and/or Cb bf16 outputs.
__global__ __launch_bounds__(256) void mfma_gemm(
    const __bf16* __restrict__ A, const __bf16* __restrict__ B,
    const float* __restrict__ bias, const float* __restrict__ E,
    float* __restrict__ Cf, __bf16* __restrict__ Cb,
    int K, int lda, int ldb, int ldc, int nMax,
    long sAo, long sAi, long sBo, long sBi, int zInner, long sC, int act)
{
    __shared__ __bf16 As[128 * 32];
    __shared__ __bf16 Bs[128 * 32];
    int z = blockIdx.z;
    long aBase = (long)(z / zInner) * sAo + (long)(z % zInner) * sAi;
    long bBase = (long)(z / zInner) * sBo + (long)(z % zInner) * sBi;
    long cBase = (long)z * sC;
    int m0 = blockIdx.y * 128, n0 = blockIdx.x * 128;
    int tid = threadIdx.x;
    int wave = tid >> 6, lane = tid & 63;
    int wm = wave >> 1, wn = wave & 1;

    int e0 = tid, e1 = tid + 256;
    const __bf16* Ag0 = A + aBase + (long)(m0 + (e0 >> 2)) * lda + (e0 & 3) * 8;
    const __bf16* Ag1 = A + aBase + (long)(m0 + (e1 >> 2)) * lda + (e1 & 3) * 8;
    const __bf16* Bg0 = B + bBase + (long)(n0 + (e0 >> 2)) * ldb + (e0 & 3) * 8;
    const __bf16* Bg1 = B + bBase + (long)(n0 + (e1 >> 2)) * ldb + (e1 & 3) * 8;
    __bf16* As0 = As + e0 * 8; __bf16* As1 = As + e1 * 8;
    __bf16* Bs0 = Bs + e0 * 8; __bf16* Bs1 = Bs + e1 * 8;

    f32x4 acc[4][4];
#pragma unroll
    for (int i = 0; i < 4; i++)
#pragma unroll
        for (int j = 0; j < 4; j++) acc[i][j] = (f32x4){0.f, 0.f, 0.f, 0.f};

    const bf16x8* Asv = (const bf16x8*)As;
    const bf16x8* Bsv = (const bf16x8*)Bs;
    int arow = wm * 64 + (lane & 15);
    int brow = wn * 64 + (lane & 15);
    int quad = lane >> 4;

    for (int k0 = 0; k0 < K; k0 += 32) {
        glds16(Ag0 + k0, As0); glds16(Ag1 + k0, As1);
        glds16(Bg0 + k0, Bs0); glds16(Bg1 + k0, Bs1);
        __syncthreads();
        bf16x8 af[4], bfr[4];
#pragma unroll
        for (int mi = 0; mi < 4; mi++) af[mi] = Asv[(arow + mi * 16) * 4 + quad];
#pragma unroll
        for (int ni = 0; ni < 4; ni++) bfr[ni] = Bsv[(brow + ni * 16) * 4 + quad];
#pragma unroll
        for (int mi = 0; mi < 4; mi++)
#pragma unroll
            for (int ni = 0; ni < 4; ni++)
                acc[mi][ni] = __builtin_amdgcn_mfma_f32_16x16x32_bf16(
                    af[mi], bfr[ni], acc[mi][ni], 0, 0, 0);
        __syncthreads();
    }

    int crow = m0 + wm * 64 + (lane >> 4) * 4;
    int ccol = n0 + wn * 64 + (lane & 15);
    float bv[4];
#pragma unroll
    for (int ni = 0; ni < 4; ni++) {
        int col = ccol + ni * 16;
        bv[ni] = (bias && col < nMax) ? bias[col] : 0.f;
    }
#pragma unroll
    for (int mi = 0; mi < 4; mi++) {
#pragma unroll
        for (int ni = 0; ni < 4; ni++) {
            int col = ccol + ni * 16;
            if (col >= nMax) continue;
#pragma unroll
            for (int r = 0; r < 4; r++) {
                float v = acc[mi][ni][r] + bv[ni];
                long idx = cBase + (long)(crow + mi * 16 + r) * ldc + col;
                if (act == 1) v = fmaxf(v, 0.f);
                else if (act == 2) v = (v > 0.f) ? v : expm1f(v);
                else if (act == 3) { float e = E[idx]; float g = 0.6f * sigf(v); v = (1.f - g) * e + g * v; }
                else if (act == 4) { float e = E[idx]; v = fmaxf(v, 0.f); float g = sigf(e); v = g * v + (1.f - g) * e; }
                if (Cf) Cf[idx] = v;
                if (Cb) Cb[idx] = (__bf16)v;
            }
        }
    }
}

// ---------------- casts ----------------
__global__ void cast_bf16_kernel(const float* __restrict__ in, __bf16* __restrict__ out, long n4)
{
    long i = (long)blockIdx.x * blockDim.x + threadIdx.x;
    if (i < n4) {
        float4 v = ((const float4*)in)[i];
        bf16x4 o; o[0] = (__bf16)v.x; o[1] = (__bf16)v.y; o[2] = (__bf16)v.z; o[3] = (__bf16)v.w;
        ((bf16x4*)out)[i] = o;
    }
}

// fp32 [R][C] -> bf16 [C][R], batched over z (R,C multiples of 32)
__global__ __launch_bounds__(256) void castT_kernel(
    const float* __restrict__ in, __bf16* __restrict__ out, int R, int C)
{
    __shared__ float t[32][33];
    long zo = (long)blockIdx.z * R * C;
    int r0 = blockIdx.y * 32, c0 = blockIdx.x * 32;
    int tid = threadIdx.x;
    int r = tid >> 3, c4 = (tid & 7) * 4;
    float4 v = *(const float4*)(in + zo + (long)(r0 + r) * C + c0 + c4);
    t[r][c4] = v.x; t[r][c4 + 1] = v.y; t[r][c4 + 2] = v.z; t[r][c4 + 3] = v.w;
    __syncthreads();
    int c = tid >> 3, r4 = (tid & 7) * 4;
    bf16x4 o;
    o[0] = (__bf16)t[r4 + 0][c]; o[1] = (__bf16)t[r4 + 1][c];
    o[2] = (__bf16)t[r4 + 2][c]; o[3] = (__bf16)t[r4 + 3][c];
    *(bf16x4*)(out + zo + (long)(c0 + c) * R + r0 + r4) = o;
}

// ---------------- attention softmax + head-mean -> adj_ag (bf16 in/out) -------
__global__ __launch_bounds__(256) void softmax_combine(
    const __bf16* __restrict__ scores, const int* __restrict__ attn_mask,
    __bf16* __restrict__ adj_agb, int b0)
{
    const int S = 512;
    int s = blockIdx.x, bl = blockIdx.y, b = b0 + bl;
    int tid = threadIdx.x;
    const float scale = 0.1020620726159658f;  // 1/sqrt(96)
    int t0 = tid, t1 = tid + 256;
    int cm0 = attn_mask[b * S + t0], cm1 = attn_mask[b * S + t1];
    float vals[8][2], part[8];
#pragma unroll
    for (int h = 0; h < 8; ++h) {
        long rb = ((long)(bl * 8 + h) * S + s) * S;
        float r0 = (float)scores[rb + t0], r1 = (float)scores[rb + t1];
        vals[h][0] = cm0 ? __expf(r0 * scale) : 0.f;
        vals[h][1] = cm1 ? __expf(r1 * scale) : 0.f;
        part[h] = vals[h][0] + vals[h][1];
    }
    __shared__ float red[4][8];
    __shared__ float linv[8];
    int lane = tid & 63, w = tid >> 6;
#pragma unroll
    for (int h = 0; h < 8; ++h) {
        float v = part[h];
        for (int o = 32; o > 0; o >>= 1) v += __shfl_down(v, o);
        if (lane == 0) red[w][h] = v;
    }
    __syncthreads();
    if (tid < 8) {
        float l = red[0][tid] + red[1][tid] + red[2][tid] + red[3][tid];
        linv[tid] = 1.f / fmaxf(l, 1e-30f);
    }
    __syncthreads();
    float rowmask = attn_mask[b * S + s] ? 1.f : 0.f;
    float a0 = 0.f, a1 = 0.f;
#pragma unroll
    for (int h = 0; h < 8; ++h) { a0 += vals[h][0] * linv[h]; a1 += vals[h][1] * linv[h]; }
    a0 *= 0.125f; a1 *= 0.125f;
    if (t0 == s) a0 = 1.f;
    if (t1 == s) a1 = 1.f;
    long ob = ((long)b * S + s) * S;
    adj_agb[ob + t0] = (__bf16)(rowmask * a0);
    adj_agb[ob + t1] = (__bf16)(rowmask * a1);
}

// ---------------- row L2-normalize + bf16 copy ----------------
__global__ __launch_bounds__(128) void rownorm(
    const float* __restrict__ h1, const float* __restrict__ h2,
    __bf16* __restrict__ h1b, __bf16* __restrict__ h2b, int Dm)
{
    const float* p = (blockIdx.y ? h2 : h1) + (long)blockIdx.x * Dm;
    __bf16* pb = (blockIdx.y ? h2b : h1b) + (long)blockIdx.x * Dm;
    int tid = threadIdx.x;
    float ss = 0.f;
    for (int i = tid; i < Dm; i += 128) { float v = p[i]; ss += v * v; }
    for (int o = 32; o > 0; o >>= 1) ss += __shfl_down(ss, o);
    __shared__ float sb[2];
    __shared__ float scale;
    if ((tid & 63) == 0) sb[tid >> 6] = ss;
    __syncthreads();
    if (tid == 0) scale = 1.f / fmaxf(sqrtf(sb[0] + sb[1]), 1e-12f);
    __syncthreads();
    for (int i = tid; i < Dm; i += 128) pb[i] = (__bf16)(p[i] * scale);
}

// ---------------- fused symmetric scope loss per (b,s) row (bf16 G) -----------
__global__ __launch_bounds__(256) void loss_kernel(
    const __bf16* __restrict__ G11, const __bf16* __restrict__ G12,
    const __bf16* __restrict__ G21, const __bf16* __restrict__ G22,
    const int* __restrict__ s_mask, const int* __restrict__ a_mask,
    float* __restrict__ lossb)
{
    const int S = 512;
    int s = blockIdx.x, b = blockIdx.y;
    int tid = threadIdx.x;
    if (a_mask[b * S + s] == 0) {
        if (tid == 0) lossb[b * S + s] = 0.f;
        return;
    }
    long base = ((long)b * S + s) * S;
    const float it = 1.f / 0.07f;
    float sms = s_mask[b * S + s] ? 1.f : 0.f;
    float d12 = (float)G12[base + s], d21 = (float)G21[base + s];
    float w1i = sms * d12 * it, w2i = sms * d21 * it;
    float p[8];
#pragma unroll
    for (int h = 0; h < 8; h++) p[h] = 0.f;
#pragma unroll
    for (int j = 0; j < 2; j++) {
        int t = tid + j * 256;
        bool smt = s_mask[b * S + t] != 0;
        bool off = (t != s);
        float g11 = (float)G11[base + t], g12 = (float)G12[base + t];
        float g21 = (float)G21[base + t], g22 = (float)G22[base + t];
        float e11 = __expf(g11 * it), e12 = __expf(g12 * it);
        float e21 = __expf(g21 * it), e22 = __expf(g22 * it);
        p[2] += e11; p[3] += e12; p[6] += e22; p[7] += e21;
        if (off) {
            p[0] += smt ? e11 : 1.f;
            p[4] += smt ? e22 : 1.f;
            p[1] += smt ? __expf(g12 * w1i) : 1.f;
            p[5] += smt ? __expf(g21 * w2i) : 1.f;
        }
    }
    __shared__ float red[4][8];
    int lane = tid & 63, w = tid >> 6;
#pragma unroll
    for (int h = 0; h < 8; h++) {
        float v = p[h];
        for (int o = 32; o > 0; o >>= 1) v += __shfl_down(v, o);
        if (lane == 0) red[w][h] = v;
    }
    __syncthreads();
    if (tid == 0) {
        float r[8];
#pragma unroll
        for (int h = 0; h < 8; h++) r[h] = red[0][h] + red[1][h] + red[2][h] + red[3][h];
        float g11ss = (float)G11[base + s], g22ss = (float)G22[base + s];
        float pos1 = __expf(w1i) + r[0] + r[1];
        float alle1 = r[2] - __expf(g11ss * it) + r[3];
        float pos2 = __expf(w2i) + r[4] + r[5];
        float alle2 = r[6] - __expf(g22ss * it) + r[7];
        lossb[b * S + s] = 0.5f * ((__logf(alle1) - __logf(pos1)) +
                                   (__logf(alle2) - __logf(pos2)));
    }
}

__global__ __launch_bounds__(256) void final_reduce(
    const float* __restrict__ lossb, float* __restrict__ out, int n)
{
    int tid = threadIdx.x;
    float s = 0.f;
    for (int i = tid; i < n; i += 256) s += lossb[i];
    for (int o = 32; o > 0; o >>= 1) s += __shfl_down(s, o);
    __shared__ float sb[4];
    if ((tid & 63) == 0) sb[tid >> 6] = s;
    __syncthreads();
    if (tid == 0) out[0] = (sb[0] + sb[1] + sb[2] + sb[3]) / (float)n;
}

// ---------------- host ----------------
static inline void mg(hipStream_t st, const __bf16* A, const __bf16* B, const float* bias,
                      const float* E, float* Cf, __bf16* Cb,
                      int M, int Npad, int nMax, int K, int lda, int ldb, int ldc,
                      long sAo, long sAi, long sBo, long sBi, int zInner, long sC, int nz,
                      int act)
{
    dim3 g(Npad / 128, M / 128, nz);
    mfma_gemm<<<g, 256, 0, st>>>(A, B, bias, E, Cf, Cb, K, lda, ldb, ldc, nMax,
                                 sAo, sAi, sBo, sBi, zInner, sC, act);
}

static inline void castT(hipStream_t st, const float* in, __bf16* out, int R, int C, int nz)
{
    castT_kernel<<<dim3(C / 32, R / 32, nz), 256, 0, st>>>(in, out, R, C);
}

extern "C" void kernel_launch(void* const* d_in, const int* in_sizes, int n_in,
                              void* d_out, int out_size, void* d_ws, size_t ws_size,
                              hipStream_t stream)
{
    const int B = 32, S = 512, D = 768, Mm = 384;
    const int MT = B * S;  // 16384
    const float* X    = (const float*)d_in[0];
    const float* adjm = (const float*)d_in[1];
    const int* attn_mask = (const int*)d_in[2];
    const int* s_mask    = (const int*)d_in[3];
    const int* a_mask    = (const int*)d_in[4];
    const float* Wq = (const float*)d_in[5],  *bq = (const float*)d_in[6];
    const float* Wk = (const float*)d_in[7],  *bk = (const float*)d_in[8];
    const float* semW0 = (const float*)d_in[9],  *semb0 = (const float*)d_in[10];
    const float* semW1 = (const float*)d_in[11], *semb1 = (const float*)d_in[12];
    const float* depW0 = (const float*)d_in[13], *depb0 = (const float*)d_in[14];
    const float* depW1 = (const float*)d_in[15], *depb1 = (const float*)d_in[16];
    const float* fc1W = (const float*)d_in[17], *fc1b = (const float*)d_in[18];
    const float* fc2W = (const float*)d_in[19], *fc2b = (const float*)d_in[20];
    const float* fc3W = (const float*)d_in[21], *fc3b = (const float*)d_in[22];
    const float* fc4W = (const float*)d_in[23], *fc4b = (const float*)d_in[24];

    char* ws = (char*)d_ws;
    const size_t MB = 1u << 20;
    const size_t KB = 1u << 10;

    // rotating regions
    __bf16* Xb      = (__bf16*)(ws + 0 * MB);     // 24MB
    __bf16* adj_agb = (__bf16*)(ws + 24 * MB);    // 16MB \ contiguous
    __bf16* adjmb   = (__bf16*)(ws + 40 * MB);    // 16MB /
    __bf16* qkb     = (__bf16*)(ws + 56 * MB);    // 48MB [16384][1536] (attn)
    __bf16* scoreB  = (__bf16*)(ws + 104 * MB);   // 64MB chunk (attn)
    __bf16* P64     = (__bf16*)(ws + 56 * MB);    // 25.2MB [64][384][512] (layers)
    float*  Isem    = (float*)(ws + 82 * MB);     // 24MB
    __bf16* Icomb   = (__bf16*)(ws + 106 * MB);   // 12MB
    float*  H       = (float*)(ws + 118 * MB);    // 24MB
    __bf16* Hb      = (__bf16*)(ws + 142 * MB);   // 12MB (l0 out; rewritten l1)
    __bf16* Isemb   = (__bf16*)(ws + 154 * MB);   // 12MB
    __bf16* t1b     = (__bf16*)(ws + 0 * MB);     // 1MB (proj; Xb dead)
    float*  h1      = (float*)(ws + 4 * MB);      // 24MB (adj regions dead)
    float*  h2      = (float*)(ws + 28 * MB);     // 24MB
    __bf16* h1b     = (__bf16*)(ws + 56 * MB);    // 12MB \ contiguous (P64 dead)
    __bf16* h2b     = (__bf16*)(ws + 68 * MB);    // 12MB /
    __bf16* G11     = (__bf16*)(ws + 80 * MB);    // 16MB x4 contiguous
    __bf16* G12     = (__bf16*)(ws + 96 * MB);
    __bf16* G21     = (__bf16*)(ws + 112 * MB);
    __bf16* G22     = (__bf16*)(ws + 128 * MB);   // ends 144MB

    // permanent weights @168MB
    char* wreg = ws + 168 * MB;
    __bf16* WqkT   = (__bf16*)(wreg + 0 * KB);     // [1536][768] 2304KB
    __bf16* semW0T = (__bf16*)(wreg + 2304 * KB);  // [384][768] 576KB \ contiguous
    __bf16* depW0T = (__bf16*)(wreg + 2880 * KB);  // 576KB            /
    __bf16* fc4WT  = (__bf16*)(wreg + 3456 * KB);  // 576KB
    __bf16* semW1T = (__bf16*)(wreg + 4032 * KB);  // [384][384] 288KB \ contiguous
    __bf16* depW1T = (__bf16*)(wreg + 4320 * KB);  // 288KB            /
    __bf16* fc3WT  = (__bf16*)(wreg + 4608 * KB);  // 288KB
    __bf16* fc1WT  = (__bf16*)(wreg + 4896 * KB);  // [128 pad][384] 96KB
    __bf16* fc2WT  = (__bf16*)(wreg + 4992 * KB);  // [384][32] 24KB
    float*  bqk    = (float*)(wreg + 5016 * KB);   // [1536]
    float*  lossb  = (float*)(wreg + 5032 * KB);   // 64KB

    long nSD = (long)S * D, nSM = (long)S * Mm, nSS = (long)S * S;
    long nPM = (long)Mm * S;  // P slice 384*512

    // ---- casts ----
    cast_bf16_kernel<<<(MT * D / 4 + 255) / 256, 256, 0, stream>>>(X, Xb, (long)MT * D / 4);
    cast_bf16_kernel<<<((long)B * nSS / 4 + 255) / 256, 256, 0, stream>>>(adjm, adjmb, (long)B * nSS / 4);
    castT(stream, Wq, WqkT, D, D, 1);
    castT(stream, Wk, WqkT + (long)D * D, D, D, 1);
    castT(stream, semW0, semW0T, D, Mm, 1);
    castT(stream, depW0, depW0T, D, Mm, 1);
    castT(stream, fc4W, fc4WT, D, Mm, 1);
    castT(stream, semW1, semW1T, Mm, Mm, 1);
    castT(stream, depW1, depW1T, Mm, Mm, 1);
    castT(stream, fc3W, fc3WT, Mm, Mm, 1);
    castT(stream, fc1W, fc1WT, Mm, 32, 1);
    hipMemsetAsync(fc1WT + 32 * Mm, 0, (size_t)96 * Mm * 2, stream);
    castT(stream, fc2W, fc2WT, 32, Mm, 1);
    hipMemcpyAsync(bqk, bq, D * 4, hipMemcpyDeviceToDevice, stream);
    hipMemcpyAsync(bqk + D, bk, D * 4, hipMemcpyDeviceToDevice, stream);

    // ---- fused q|k projection ----
    mg(stream, Xb, WqkT, bqk, nullptr, nullptr, qkb, MT, 1536, 1536, D,
       D, D, 1536, 0, 0, 0, 0, 1, 0, 1, 0);

    // ---- attention: 2 chunks of 16 batches (z=128) ----
    for (int c = 0; c < 2; c++) {
        const __bf16* qc = qkb + (long)c * 16 * S * 1536;
        mg(stream, qc, qc + 768, nullptr, nullptr, nullptr, scoreB, S, S, S, 96,
           1536, 1536, S, (long)S * 1536, 96, (long)S * 1536, 96, 8, nSS, 128, 0);
        softmax_combine<<<dim3(S, 16), 256, 0, stream>>>(scoreB, attn_mask, adj_agb, c * 16);
    }

    // ---- layer 0 (reassociated) ----
    // P64[z<32] = (X_b @ semW0)^T, P64[z>=32] = (X_b @ depW0)^T  (bf16 [384][512])
    mg(stream, semW0T, Xb, nullptr, nullptr, nullptr, P64, Mm, S, S, D,
       D, D, S, (long)Mm * D, 0, 0, nSD, 32, nPM, 64, 0);
    // Isem = adj_ag @ Psem + semb0
    mg(stream, adj_agb, P64, semb0, nullptr, Isem, nullptr, S, Mm, Mm, S,
       S, S, Mm, 0, nSS, 0, nPM, 32, nSM, 32, 0);
    // Icom = gcn_combine(Isem, adjm @ Pdep + depb0)
    mg(stream, adjmb, P64 + 32 * nPM, depb0, Isem, nullptr, Icomb, S, Mm, Mm, S,
       S, S, Mm, 0, nSS, 0, nPM, 32, nSM, 32, 3);
    // H = X @ fc4W + fc4b
    mg(stream, Xb, fc4WT, fc4b, nullptr, H, nullptr, MT, Mm, Mm, D,
       D, D, Mm, 0, 0, 0, 0, 1, 0, 1, 0);
    // H = gate(H, relu(Icom @ fc3W + fc3b))  (in place), + bf16 copy Hb
    mg(stream, Icomb, fc3WT, fc3b, H, H, Hb, MT, Mm, Mm, Mm,
       Mm, Mm, Mm, 0, 0, 0, 0, 1, 0, 1, 4);

    // ---- layer 1 (reassociated) ----
    mg(stream, semW1T, Hb, nullptr, nullptr, nullptr, P64, Mm, S, S, Mm,
       Mm, Mm, S, (long)Mm * Mm, 0, 0, nSM, 32, nPM, 64, 0);
    mg(stream, adj_agb, P64, semb1, nullptr, Isem, Isemb, S, Mm, Mm, S,
       S, S, Mm, 0, nSS, 0, nPM, 32, nSM, 32, 0);
    mg(stream, adjmb, P64 + 32 * nPM, depb1, Isem, nullptr, Icomb, S, Mm, Mm, S,
       S, S, Mm, 0, nSS, 0, nPM, 32, nSM, 32, 3);
    mg(stream, Icomb, fc3WT, fc3b, H, nullptr, Hb, MT, Mm, Mm, Mm,
       Mm, Mm, Mm, 0, 0, 0, 0, 1, 0, 1, 4);

    // ---- projection heads ----
    mg(stream, Hb, fc1WT, fc1b, nullptr, nullptr, t1b, MT, 128, 32, Mm,
       Mm, Mm, 32, 0, 0, 0, 0, 1, 0, 1, 2);
    mg(stream, t1b, fc2WT, fc2b, nullptr, h1, nullptr, MT, Mm, Mm, 32,
       32, 32, Mm, 0, 0, 0, 0, 1, 0, 1, 0);
    mg(stream, Isemb, fc1WT, fc1b, nullptr, nullptr, t1b, MT, 128, 32, Mm,
       Mm, Mm, 32, 0, 0, 0, 0, 1, 0, 1, 2);
    mg(stream, t1b, fc2WT, fc2b, nullptr, h2, nullptr, MT, Mm, Mm, 32,
       32, 32, Mm, 0, 0, 0, 0, 1, 0, 1, 0);

    rownorm<<<dim3(MT, 2), 128, 0, stream>>>(h1, h2, h1b, h2b, Mm);

    // ---- Gram matrices (bf16 out): z<32 -> B=h1b, z>=32 -> B=h2b ----
    mg(stream, h1b, h1b, nullptr, nullptr, nullptr, G11, S, S, S, Mm,
       Mm, Mm, S, 0, nSM, 32 * nSM, nSM, 32, nSS, 64, 0);   // G11 | G12
    mg(stream, h2b, h1b, nullptr, nullptr, nullptr, G21, S, S, S, Mm,
       Mm, Mm, S, 0, nSM, 32 * nSM, nSM, 32, nSS, 64, 0);   // G21 | G22

    // ---- loss ----
    loss_kernel<<<dim3(S, B), 256, 0, stream>>>(G11, G12, G21, G22, s_mask, a_mask, lossb);
    final_reduce<<<1, 256, 0, stream>>>(lossb, (float*)d_out, MT);
}

// Round 5
// 906.429 us; speedup vs baseline: 4.1596x; 1.0464x over previous
//
#include <hip/hip_runtime.h>
#include <math.h>

// DASCO forward, round 5: (R4) + grid-transposed block mapping (m on x -> all
// n-blocks sharing an A-tile land on one XCD when gridDim.x%8==0) + double-
// buffered LDS K-loop (loads for tile k+1 in flight during tile-k MFMAs,
// one barrier per iteration). B=32, S=512, D=768, M=384.

typedef __bf16 bf16x8 __attribute__((ext_vector_type(8)));
typedef __bf16 bf16x4 __attribute__((ext_vector_type(4)));
typedef float f32x4 __attribute__((ext_vector_type(4)));

__device__ __forceinline__ void glds16(const void* g, void* l) {
    __builtin_amdgcn_global_load_lds(
        (const __attribute__((address_space(1))) unsigned*)g,
        (__attribute__((address_space(3))) unsigned*)l, 16, 0, 0);
}

__device__ __forceinline__ float sigf(float x) { return 1.f / (1.f + __expf(-x)); }

// ---------------- bf16 MFMA GEMM, 128x128 tile, K%32==0, M%128==0, Npad%128==0 --
// C[z][m][n] = sum_k A[z][m][k]*B[z][n][k] (+bias), epilogue act:
// 0 none; 1 relu; 2 elu; 3 gcn-combine(E=Isem); 4 relu+gate(E=Hold)
// writes masked to n < nMax. Cf fp32 and/or Cb bf16 outputs.
// Grid: x = m-blocks, y = n-blocks, z = batch.
__global__ __launch_bounds__(256) void mfma_gemm(
    const __bf16* __restrict__ A, const __bf16* __restrict__ B,
    const float* __restrict__ bias, const float* __restrict__ E,
    float* __restrict__ Cf, __bf16* __restrict__ Cb,
    int K, int lda, int ldb, int ldc, int nMax,
    long sAo, long sAi, long sBo, long sBi, int zInner, long sC, int act)
{
    __shared__ __bf16 As[2][128 * 32];
    __shared__ __bf16 Bs[2][128 * 32];
    int z = blockIdx.z;
    long aBase = (long)(z / zInner) * sAo + (long)(z % zInner) * sAi;
    long bBase = (long)(z / zInner) * sBo + (long)(z % zInner) * sBi;
    long cBase = (long)z * sC;
    int m0 = blockIdx.x * 128, n0 = blockIdx.y * 128;   // m innermost
    int tid = threadIdx.x;
    int wave = tid >> 6, lane = tid & 63;
    int wm = wave >> 1, wn = wave & 1;

    // staging: element e in [0,512): row=e>>2 (0..127), kpart=(e&3)*8
    int e0 = tid, e1 = tid + 256;
    const __bf16* Ag0 = A + aBase + (long)(m0 + (e0 >> 2)) * lda + (e0 & 3) * 8;
    const __bf16* Ag1 = A + aBase + (long)(m0 + (e1 >> 2)) * lda + (e1 & 3) * 8;
    const __bf16* Bg0 = B + bBase + (long)(n0 + (e0 >> 2)) * ldb + (e0 & 3) * 8;
    const __bf16* Bg1 = B + bBase + (long)(n0 + (e1 >> 2)) * ldb + (e1 & 3) * 8;

    f32x4 acc[4][4];
#pragma unroll
    for (int i = 0; i < 4; i++)
#pragma unroll
        for (int j = 0; j < 4; j++) acc[i][j] = (f32x4){0.f, 0.f, 0.f, 0.f};

    int arow = wm * 64 + (lane & 15);
    int brow = wn * 64 + (lane & 15);
    int quad = lane >> 4;

    // prologue: tile 0 -> buffer 0
    glds16(Ag0, As[0] + e0 * 8); glds16(Ag1, As[0] + e1 * 8);
    glds16(Bg0, Bs[0] + e0 * 8); glds16(Bg1, Bs[0] + e1 * 8);

    int cur = 0;
    for (int k0 = 0; k0 < K; k0 += 32) {
        __syncthreads();   // drains vmcnt -> buf[cur] ready; prev readers done
        if (k0 + 32 < K) {
            int nk = k0 + 32, nb = cur ^ 1;
            glds16(Ag0 + nk, As[nb] + e0 * 8); glds16(Ag1 + nk, As[nb] + e1 * 8);
            glds16(Bg0 + nk, Bs[nb] + e0 * 8); glds16(Bg1 + nk, Bs[nb] + e1 * 8);
        }
        const bf16x8* Asv = (const bf16x8*)As[cur];
        const bf16x8* Bsv = (const bf16x8*)Bs[cur];
        bf16x8 af[4], bfr[4];
#pragma unroll
        for (int mi = 0; mi < 4; mi++) af[mi] = Asv[(arow + mi * 16) * 4 + quad];
#pragma unroll
        for (int ni = 0; ni < 4; ni++) bfr[ni] = Bsv[(brow + ni * 16) * 4 + quad];
#pragma unroll
        for (int mi = 0; mi < 4; mi++)
#pragma unroll
            for (int ni = 0; ni < 4; ni++)
                acc[mi][ni] = __builtin_amdgcn_mfma_f32_16x16x32_bf16(
                    af[mi], bfr[ni], acc[mi][ni], 0, 0, 0);
        cur ^= 1;
    }

    int crow = m0 + wm * 64 + (lane >> 4) * 4;
    int ccol = n0 + wn * 64 + (lane & 15);
    float bv[4];
#pragma unroll
    for (int ni = 0; ni < 4; ni++) {
        int col = ccol + ni * 16;
        bv[ni] = (bias && col < nMax) ? bias[col] : 0.f;
    }
#pragma unroll
    for (int mi = 0; mi < 4; mi++) {
#pragma unroll
        for (int ni = 0; ni < 4; ni++) {
            int col = ccol + ni * 16;
            if (col >= nMax) continue;
#pragma unroll
            for (int r = 0; r < 4; r++) {
                float v = acc[mi][ni][r] + bv[ni];
                long idx = cBase + (long)(crow + mi * 16 + r) * ldc + col;
                if (act == 1) v = fmaxf(v, 0.f);
                else if (act == 2) v = (v > 0.f) ? v : expm1f(v);
                else if (act == 3) { float e = E[idx]; float g = 0.6f * sigf(v); v = (1.f - g) * e + g * v; }
                else if (act == 4) { float e = E[idx]; v = fmaxf(v, 0.f); float g = sigf(e); v = g * v + (1.f - g) * e; }
                if (Cf) Cf[idx] = v;
                if (Cb) Cb[idx] = (__bf16)v;
            }
        }
    }
}

// ---------------- casts ----------------
__global__ void cast_bf16_kernel(const float* __restrict__ in, __bf16* __restrict__ out, long n4)
{
    long i = (long)blockIdx.x * blockDim.x + threadIdx.x;
    if (i < n4) {
        float4 v = ((const float4*)in)[i];
        bf16x4 o; o[0] = (__bf16)v.x; o[1] = (__bf16)v.y; o[2] = (__bf16)v.z; o[3] = (__bf16)v.w;
        ((bf16x4*)out)[i] = o;
    }
}

// fp32 [R][C] -> bf16 [C][R], batched over z (R,C multiples of 32)
__global__ __launch_bounds__(256) void castT_kernel(
    const float* __restrict__ in, __bf16* __restrict__ out, int R, int C)
{
    __shared__ float t[32][33];
    long zo = (long)blockIdx.z * R * C;
    int r0 = blockIdx.y * 32, c0 = blockIdx.x * 32;
    int tid = threadIdx.x;
    int r = tid >> 3, c4 = (tid & 7) * 4;
    float4 v = *(const float4*)(in + zo + (long)(r0 + r) * C + c0 + c4);
    t[r][c4] = v.x; t[r][c4 + 1] = v.y; t[r][c4 + 2] = v.z; t[r][c4 + 3] = v.w;
    __syncthreads();
    int c = tid >> 3, r4 = (tid & 7) * 4;
    bf16x4 o;
    o[0] = (__bf16)t[r4 + 0][c]; o[1] = (__bf16)t[r4 + 1][c];
    o[2] = (__bf16)t[r4 + 2][c]; o[3] = (__bf16)t[r4 + 3][c];
    *(bf16x4*)(out + zo + (long)(c0 + c) * R + r0 + r4) = o;
}

// ---------------- attention softmax + head-mean -> adj_ag (bf16 in/out) -------
__global__ __launch_bounds__(256) void softmax_combine(
    const __bf16* __restrict__ scores, const int* __restrict__ attn_mask,
    __bf16* __restrict__ adj_agb, int b0)
{
    const int S = 512;
    int s = blockIdx.x, bl = blockIdx.y, b = b0 + bl;
    int tid = threadIdx.x;
    const float scale = 0.1020620726159658f;  // 1/sqrt(96)
    int t0 = tid, t1 = tid + 256;
    int cm0 = attn_mask[b * S + t0], cm1 = attn_mask[b * S + t1];
    float vals[8][2], part[8];
#pragma unroll
    for (int h = 0; h < 8; ++h) {
        long rb = ((long)(bl * 8 + h) * S + s) * S;
        float r0 = (float)scores[rb + t0], r1 = (float)scores[rb + t1];
        vals[h][0] = cm0 ? __expf(r0 * scale) : 0.f;
        vals[h][1] = cm1 ? __expf(r1 * scale) : 0.f;
        part[h] = vals[h][0] + vals[h][1];
    }
    __shared__ float red[4][8];
    __shared__ float linv[8];
    int lane = tid & 63, w = tid >> 6;
#pragma unroll
    for (int h = 0; h < 8; ++h) {
        float v = part[h];
        for (int o = 32; o > 0; o >>= 1) v += __shfl_down(v, o);
        if (lane == 0) red[w][h] = v;
    }
    __syncthreads();
    if (tid < 8) {
        float l = red[0][tid] + red[1][tid] + red[2][tid] + red[3][tid];
        linv[tid] = 1.f / fmaxf(l, 1e-30f);
    }
    __syncthreads();
    float rowmask = attn_mask[b * S + s] ? 1.f : 0.f;
    float a0 = 0.f, a1 = 0.f;
#pragma unroll
    for (int h = 0; h < 8; ++h) { a0 += vals[h][0] * linv[h]; a1 += vals[h][1] * linv[h]; }
    a0 *= 0.125f; a1 *= 0.125f;
    if (t0 == s) a0 = 1.f;
    if (t1 == s) a1 = 1.f;
    long ob = ((long)b * S + s) * S;
    adj_agb[ob + t0] = (__bf16)(rowmask * a0);
    adj_agb[ob + t1] = (__bf16)(rowmask * a1);
}

// ---------------- row L2-normalize + bf16 copy ----------------
__global__ __launch_bounds__(128) void rownorm(
    const float* __restrict__ h1, const float* __restrict__ h2,
    __bf16* __restrict__ h1b, __bf16* __restrict__ h2b, int Dm)
{
    const float* p = (blockIdx.y ? h2 : h1) + (long)blockIdx.x * Dm;
    __bf16* pb = (blockIdx.y ? h2b : h1b) + (long)blockIdx.x * Dm;
    int tid = threadIdx.x;
    float ss = 0.f;
    for (int i = tid; i < Dm; i += 128) { float v = p[i]; ss += v * v; }
    for (int o = 32; o > 0; o >>= 1) ss += __shfl_down(ss, o);
    __shared__ float sb[2];
    __shared__ float scale;
    if ((tid & 63) == 0) sb[tid >> 6] = ss;
    __syncthreads();
    if (tid == 0) scale = 1.f / fmaxf(sqrtf(sb[0] + sb[1]), 1e-12f);
    __syncthreads();
    for (int i = tid; i < Dm; i += 128) pb[i] = (__bf16)(p[i] * scale);
}

// ---------------- fused symmetric scope loss per (b,s) row (bf16 G) -----------
__global__ __launch_bounds__(256) void loss_kernel(
    const __bf16* __restrict__ G11, const __bf16* __restrict__ G12,
    const __bf16* __restrict__ G21, const __bf16* __restrict__ G22,
    const int* __restrict__ s_mask, const int* __restrict__ a_mask,
    float* __restrict__ lossb)
{
    const int S = 512;
    int s = blockIdx.x, b = blockIdx.y;
    int tid = threadIdx.x;
    if (a_mask[b * S + s] == 0) {
        if (tid == 0) lossb[b * S + s] = 0.f;
        return;
    }
    long base = ((long)b * S + s) * S;
    const float it = 1.f / 0.07f;
    float sms = s_mask[b * S + s] ? 1.f : 0.f;
    float d12 = (float)G12[base + s], d21 = (float)G21[base + s];
    float w1i = sms * d12 * it, w2i = sms * d21 * it;
    float p[8];
#pragma unroll
    for (int h = 0; h < 8; h++) p[h] = 0.f;
#pragma unroll
    for (int j = 0; j < 2; j++) {
        int t = tid + j * 256;
        bool smt = s_mask[b * S + t] != 0;
        bool off = (t != s);
        float g11 = (float)G11[base + t], g12 = (float)G12[base + t];
        float g21 = (float)G21[base + t], g22 = (float)G22[base + t];
        float e11 = __expf(g11 * it), e12 = __expf(g12 * it);
        float e21 = __expf(g21 * it), e22 = __expf(g22 * it);
        p[2] += e11; p[3] += e12; p[6] += e22; p[7] += e21;
        if (off) {
            p[0] += smt ? e11 : 1.f;
            p[4] += smt ? e22 : 1.f;
            p[1] += smt ? __expf(g12 * w1i) : 1.f;
            p[5] += smt ? __expf(g21 * w2i) : 1.f;
        }
    }
    __shared__ float red[4][8];
    int lane = tid & 63, w = tid >> 6;
#pragma unroll
    for (int h = 0; h < 8; h++) {
        float v = p[h];
        for (int o = 32; o > 0; o >>= 1) v += __shfl_down(v, o);
        if (lane == 0) red[w][h] = v;
    }
    __syncthreads();
    if (tid == 0) {
        float r[8];
#pragma unroll
        for (int h = 0; h < 8; h++) r[h] = red[0][h] + red[1][h] + red[2][h] + red[3][h];
        float g11ss = (float)G11[base + s], g22ss = (float)G22[base + s];
        float pos1 = __expf(w1i) + r[0] + r[1];
        float alle1 = r[2] - __expf(g11ss * it) + r[3];
        float pos2 = __expf(w2i) + r[4] + r[5];
        float alle2 = r[6] - __expf(g22ss * it) + r[7];
        lossb[b * S + s] = 0.5f * ((__logf(alle1) - __logf(pos1)) +
                                   (__logf(alle2) - __logf(pos2)));
    }
}

__global__ __launch_bounds__(256) void final_reduce(
    const float* __restrict__ lossb, float* __restrict__ out, int n)
{
    int tid = threadIdx.x;
    float s = 0.f;
    for (int i = tid; i < n; i += 256) s += lossb[i];
    for (int o = 32; o > 0; o >>= 1) s += __shfl_down(s, o);
    __shared__ float sb[4];
    if ((tid & 63) == 0) sb[tid >> 6] = s;
    __syncthreads();
    if (tid == 0) out[0] = (sb[0] + sb[1] + sb[2] + sb[3]) / (float)n;
}

// ---------------- host ----------------
static inline void mg(hipStream_t st, const __bf16* A, const __bf16* B, const float* bias,
                      const float* E, float* Cf, __bf16* Cb,
                      int M, int Npad, int nMax, int K, int lda, int ldb, int ldc,
                      long sAo, long sAi, long sBo, long sBi, int zInner, long sC, int nz,
                      int act)
{
    dim3 g(M / 128, Npad / 128, nz);   // m innermost
    mfma_gemm<<<g, 256, 0, st>>>(A, B, bias, E, Cf, Cb, K, lda, ldb, ldc, nMax,
                                 sAo, sAi, sBo, sBi, zInner, sC, act);
}

static inline void castT(hipStream_t st, const float* in, __bf16* out, int R, int C, int nz)
{
    castT_kernel<<<dim3(C / 32, R / 32, nz), 256, 0, st>>>(in, out, R, C);
}

extern "C" void kernel_launch(void* const* d_in, const int* in_sizes, int n_in,
                              void* d_out, int out_size, void* d_ws, size_t ws_size,
                              hipStream_t stream)
{
    const int B = 32, S = 512, D = 768, Mm = 384;
    const int MT = B * S;  // 16384
    const float* X    = (const float*)d_in[0];
    const float* adjm = (const float*)d_in[1];
    const int* attn_mask = (const int*)d_in[2];
    const int* s_mask    = (const int*)d_in[3];
    const int* a_mask    = (const int*)d_in[4];
    const float* Wq = (const float*)d_in[5],  *bq = (const float*)d_in[6];
    const float* Wk = (const float*)d_in[7],  *bk = (const float*)d_in[8];
    const float* semW0 = (const float*)d_in[9],  *semb0 = (const float*)d_in[10];
    const float* semW1 = (const float*)d_in[11], *semb1 = (const float*)d_in[12];
    const float* depW0 = (const float*)d_in[13], *depb0 = (const float*)d_in[14];
    const float* depW1 = (const float*)d_in[15], *depb1 = (const float*)d_in[16];
    const float* fc1W = (const float*)d_in[17], *fc1b = (const float*)d_in[18];
    const float* fc2W = (const float*)d_in[19], *fc2b = (const float*)d_in[20];
    const float* fc3W = (const float*)d_in[21], *fc3b = (const float*)d_in[22];
    const float* fc4W = (const float*)d_in[23], *fc4b = (const float*)d_in[24];

    char* ws = (char*)d_ws;
    const size_t MB = 1u << 20;
    const size_t KB = 1u << 10;

    // rotating regions
    __bf16* Xb      = (__bf16*)(ws + 0 * MB);     // 24MB
    __bf16* adj_agb = (__bf16*)(ws + 24 * MB);    // 16MB \ contiguous
    __bf16* adjmb   = (__bf16*)(ws + 40 * MB);    // 16MB /
    __bf16* qkb     = (__bf16*)(ws + 56 * MB);    // 48MB [16384][1536] (attn)
    __bf16* scoreB  = (__bf16*)(ws + 104 * MB);   // 64MB chunk (attn)
    __bf16* P64     = (__bf16*)(ws + 56 * MB);    // 25.2MB [64][384][512] (layers)
    float*  Isem    = (float*)(ws + 82 * MB);     // 24MB
    __bf16* Icomb   = (__bf16*)(ws + 106 * MB);   // 12MB
    float*  H       = (float*)(ws + 118 * MB);    // 24MB
    __bf16* Hb      = (__bf16*)(ws + 142 * MB);   // 12MB (l0 out; rewritten l1)
    __bf16* Isemb   = (__bf16*)(ws + 154 * MB);   // 12MB
    __bf16* t1b     = (__bf16*)(ws + 0 * MB);     // 1MB (proj; Xb dead)
    float*  h1      = (float*)(ws + 4 * MB);      // 24MB (adj regions dead)
    float*  h2      = (float*)(ws + 28 * MB);     // 24MB
    __bf16* h1b     = (__bf16*)(ws + 56 * MB);    // 12MB \ contiguous (P64 dead)
    __bf16* h2b     = (__bf16*)(ws + 68 * MB);    // 12MB /
    __bf16* G11     = (__bf16*)(ws + 80 * MB);    // 16MB x4 contiguous
    __bf16* G12     = (__bf16*)(ws + 96 * MB);
    __bf16* G21     = (__bf16*)(ws + 112 * MB);
    __bf16* G22     = (__bf16*)(ws + 128 * MB);   // ends 144MB

    // permanent weights @168MB
    char* wreg = ws + 168 * MB;
    __bf16* WqkT   = (__bf16*)(wreg + 0 * KB);     // [1536][768] 2304KB
    __bf16* semW0T = (__bf16*)(wreg + 2304 * KB);  // [384][768] 576KB \ contiguous
    __bf16* depW0T = (__bf16*)(wreg + 2880 * KB);  // 576KB            /
    __bf16* fc4WT  = (__bf16*)(wreg + 3456 * KB);  // 576KB
    __bf16* semW1T = (__bf16*)(wreg + 4032 * KB);  // [384][384] 288KB \ contiguous
    __bf16* depW1T = (__bf16*)(wreg + 4320 * KB);  // 288KB            /
    __bf16* fc3WT  = (__bf16*)(wreg + 4608 * KB);  // 288KB
    __bf16* fc1WT  = (__bf16*)(wreg + 4896 * KB);  // [128 pad][384] 96KB
    __bf16* fc2WT  = (__bf16*)(wreg + 4992 * KB);  // [384][32] 24KB
    float*  bqk    = (float*)(wreg + 5016 * KB);   // [1536]
    float*  lossb  = (float*)(wreg + 5032 * KB);   // 64KB

    long nSD = (long)S * D, nSM = (long)S * Mm, nSS = (long)S * S;
    long nPM = (long)Mm * S;  // P slice 384*512

    // ---- casts ----
    cast_bf16_kernel<<<(MT * D / 4 + 255) / 256, 256, 0, stream>>>(X, Xb, (long)MT * D / 4);
    cast_bf16_kernel<<<((long)B * nSS / 4 + 255) / 256, 256, 0, stream>>>(adjm, adjmb, (long)B * nSS / 4);
    castT(stream, Wq, WqkT, D, D, 1);
    castT(stream, Wk, WqkT + (long)D * D, D, D, 1);
    castT(stream, semW0, semW0T, D, Mm, 1);
    castT(stream, depW0, depW0T, D, Mm, 1);
    castT(stream, fc4W, fc4WT, D, Mm, 1);
    castT(stream, semW1, semW1T, Mm, Mm, 1);
    castT(stream, depW1, depW1T, Mm, Mm, 1);
    castT(stream, fc3W, fc3WT, Mm, Mm, 1);
    castT(stream, fc1W, fc1WT, Mm, 32, 1);
    hipMemsetAsync(fc1WT + 32 * Mm, 0, (size_t)96 * Mm * 2, stream);
    castT(stream, fc2W, fc2WT, 32, Mm, 1);
    hipMemcpyAsync(bqk, bq, D * 4, hipMemcpyDeviceToDevice, stream);
    hipMemcpyAsync(bqk + D, bk, D * 4, hipMemcpyDeviceToDevice, stream);

    // ---- fused q|k projection ----
    mg(stream, Xb, WqkT, bqk, nullptr, nullptr, qkb, MT, 1536, 1536, D,
       D, D, 1536, 0, 0, 0, 0, 1, 0, 1, 0);

    // ---- attention: 2 chunks of 16 batches (z=128) ----
    for (int c = 0; c < 2; c++) {
        const __bf16* qc = qkb + (long)c * 16 * S * 1536;
        mg(stream, qc, qc + 768, nullptr, nullptr, nullptr, scoreB, S, S, S, 96,
           1536, 1536, S, (long)S * 1536, 96, (long)S * 1536, 96, 8, nSS, 128, 0);
        softmax_combine<<<dim3(S, 16), 256, 0, stream>>>(scoreB, attn_mask, adj_agb, c * 16);
    }

    // ---- layer 0 (reassociated) ----
    // P64[z<32] = (X_b @ semW0)^T, P64[z>=32] = (X_b @ depW0)^T  (bf16 [384][512])
    mg(stream, semW0T, Xb, nullptr, nullptr, nullptr, P64, Mm, S, S, D,
       D, D, S, (long)Mm * D, 0, 0, nSD, 32, nPM, 64, 0);
    // Isem = adj_ag @ Psem + semb0
    mg(stream, adj_agb, P64, semb0, nullptr, Isem, nullptr, S, Mm, Mm, S,
       S, S, Mm, 0, nSS, 0, nPM, 32, nSM, 32, 0);
    // Icom = gcn_combine(Isem, adjm @ Pdep + depb0)
    mg(stream, adjmb, P64 + 32 * nPM, depb0, Isem, nullptr, Icomb, S, Mm, Mm, S,
       S, S, Mm, 0, nSS, 0, nPM, 32, nSM, 32, 3);
    // H = X @ fc4W + fc4b
    mg(stream, Xb, fc4WT, fc4b, nullptr, H, nullptr, MT, Mm, Mm, D,
       D, D, Mm, 0, 0, 0, 0, 1, 0, 1, 0);
    // H = gate(H, relu(Icom @ fc3W + fc3b))  (in place), + bf16 copy Hb
    mg(stream, Icomb, fc3WT, fc3b, H, H, Hb, MT, Mm, Mm, Mm,
       Mm, Mm, Mm, 0, 0, 0, 0, 1, 0, 1, 4);

    // ---- layer 1 (reassociated) ----
    mg(stream, semW1T, Hb, nullptr, nullptr, nullptr, P64, Mm, S, S, Mm,
       Mm, Mm, S, (long)Mm * Mm, 0, 0, nSM, 32, nPM, 64, 0);
    mg(stream, adj_agb, P64, semb1, nullptr, Isem, Isemb, S, Mm, Mm, S,
       S, S, Mm, 0, nSS, 0, nPM, 32, nSM, 32, 0);
    mg(stream, adjmb, P64 + 32 * nPM, depb1, Isem, nullptr, Icomb, S, Mm, Mm, S,
       S, S, Mm, 0, nSS, 0, nPM, 32, nSM, 32, 3);
    mg(stream, Icomb, fc3WT, fc3b, H, nullptr, Hb, MT, Mm, Mm, Mm,
       Mm, Mm, Mm, 0, 0, 0, 0, 1, 0, 1, 4);

    // ---- projection heads ----
    mg(stream, Hb, fc1WT, fc1b, nullptr, nullptr, t1b, MT, 128, 32, Mm,
       Mm, Mm, 32, 0, 0, 0, 0, 1, 0, 1, 2);
    mg(stream, t1b, fc2WT, fc2b, nullptr, h1, nullptr, MT, Mm, Mm, 32,
       32, 32, Mm, 0, 0, 0, 0, 1, 0, 1, 0);
    mg(stream, Isemb, fc1WT, fc1b, nullptr, nullptr, t1b, MT, 128, 32, Mm,
       Mm, Mm, 32, 0, 0, 0, 0, 1, 0, 1, 2);
    mg(stream, t1b, fc2WT, fc2b, nullptr, h2, nullptr, MT, Mm, Mm, 32,
       32, 32, Mm, 0, 0, 0, 0, 1, 0, 1, 0);

    rownorm<<<dim3(MT, 2), 128, 0, stream>>>(h1, h2, h1b, h2b, Mm);

    // ---- Gram matrices (bf16 out): z<32 -> B=h1b, z>=32 -> B=h2b ----
    mg(stream, h1b, h1b, nullptr, nullptr, nullptr, G11, S, S, S, Mm,
       Mm, Mm, S, 0, nSM, 32 * nSM, nSM, 32, nSS, 64, 0);   // G11 | G12
    mg(stream, h2b, h1b, nullptr, nullptr, nullptr, G21, S, S, S, Mm,
       Mm, Mm, S, 0, nSM, 32 * nSM, nSM, 32, nSS, 64, 0);   // G21 | G22

    // ---- loss ----
    loss_kernel<<<dim3(S, B), 256, 0, stream>>>(G11, G12, G21, G22, s_mask, a_mask, lossb);
    final_reduce<<<1, 256, 0, stream>>>(lossb, (float*)d_out, MT);
}